// Round 1
// baseline (315.025 us; speedup 1.0000x reference)
//
#include <hip/hip_runtime.h>
#include <hip/hip_bf16.h>

#define NN 20000      // nodes
#define NE 320000     // edges
#define FE 32         // edge feature dim
#define DIN 16
#define DNN 16
#define DGAT 64
#define HID 128
#define NG 64         // graphs

using bf16x8 = __attribute__((ext_vector_type(8))) short;
using f32x4  = __attribute__((ext_vector_type(4))) float;

static __device__ inline short f2bf(float f) {
    unsigned u = __float_as_uint(f);
    unsigned r = u + 0x7FFFu + ((u >> 16) & 1u);
    return (short)(r >> 16);
}

union ABFrag {
    bf16x8 v;
    __hip_bfloat162 h2[4];
};

// ---------------- K1: NNConv messages via on-the-fly P @ We2 MFMA ----------------
// msg[e,o] = sum_{f,i} ea[e,f]*x[src[e],i]*We[f, i*16+o]  + sum_i x[src,i]*be[i*16+o]
// P[e, k=f*16+i] built in registers; 16x16x32 bf16 MFMA, K=544 (17 ksteps, last = bias).
__global__ __launch_bounds__(256) void k_msg(
    const float* __restrict__ x, const int* __restrict__ ei,
    const float* __restrict__ ea, const float* __restrict__ We,
    const float* __restrict__ be, float* __restrict__ msg)
{
    const int lane = threadIdx.x & 63;
    const int wid  = threadIdx.x >> 6;
    const int m    = lane & 15;      // A-row (edge within tile) == B-col (n) == C col
    const int quad = lane >> 4;
    const int p    = quad >> 1;      // ea f-parity for this lane
    const int xh   = (quad & 1) * 8; // x half

    // Preload B fragments: B[k][n] = We2[k][n] = We[k>>4][(k&15)*16 + n]
    bf16x8 bfr[17];
    #pragma unroll
    for (int ks = 0; ks < 16; ++ks) {
        #pragma unroll
        for (int j = 0; j < 8; ++j) {
            int k = ks * 32 + quad * 8 + j;
            int f = k >> 4, i = k & 15;
            bfr[ks][j] = f2bf(We[f * 256 + i * 16 + m]);
        }
    }
    #pragma unroll
    for (int j = 0; j < 8; ++j) {
        int i = quad * 8 + j;
        bfr[16][j] = (quad < 2) ? f2bf(be[i * 16 + m]) : (short)0;
    }

    const int gw = blockIdx.x * 4 + wid;
    const int nw = gridDim.x * 4;
    const int* srcp = ei; // first NE entries = src

    for (int t = gw; t < NE / 16; t += nw) {
        const int e0 = t * 16;
        const int em = e0 + m;
        const int s  = srcp[em];

        float xf[8];
        {
            const float4* xr = (const float4*)(x + s * 16 + xh);
            float4 x0 = xr[0], x1 = xr[1];
            xf[0] = x0.x; xf[1] = x0.y; xf[2] = x0.z; xf[3] = x0.w;
            xf[4] = x1.x; xf[5] = x1.y; xf[6] = x1.z; xf[7] = x1.w;
        }
        float eav[16];
        {
            const float4* er = (const float4*)(ea + (long)em * 32);
            #pragma unroll
            for (int q = 0; q < 8; ++q) {
                float4 v = er[q];
                eav[2 * q]     = p ? v.y : v.x;
                eav[2 * q + 1] = p ? v.w : v.z;
            }
        }

        f32x4 acc = {0.f, 0.f, 0.f, 0.f};
        #pragma unroll
        for (int ks = 0; ks < 16; ++ks) {
            ABFrag a;
            float e = eav[ks];
            #pragma unroll
            for (int j = 0; j < 8; j += 2)
                a.h2[j >> 1] = __float22bfloat162_rn(make_float2(e * xf[j], e * xf[j + 1]));
            acc = __builtin_amdgcn_mfma_f32_16x16x32_bf16(a.v, bfr[ks], acc, 0, 0, 0);
        }
        { // bias K-step: P[e, 512+i] = x[src,i]
            ABFrag a;
            #pragma unroll
            for (int j = 0; j < 8; j += 2) {
                float f0 = (quad < 2) ? xf[j] : 0.f;
                float f1 = (quad < 2) ? xf[j + 1] : 0.f;
                a.h2[j >> 1] = __float22bfloat162_rn(make_float2(f0, f1));
            }
            acc = __builtin_amdgcn_mfma_f32_16x16x32_bf16(a.v, bfr[16], acc, 0, 0, 0);
        }
        // C/D: col = lane&15, row = quad*4 + reg
        #pragma unroll
        for (int r = 0; r < 4; ++r)
            msg[(long)(e0 + quad * 4 + r) * 16 + m] = acc[r];
    }
}

// ---------------- CSR build ----------------
__global__ void k_hist(const int* __restrict__ ei, int* __restrict__ deg) {
    int e = blockIdx.x * blockDim.x + threadIdx.x;
    if (e < NE) atomicAdd(&deg[ei[NE + e]], 1);
}

#define SCAN_K 20
__global__ __launch_bounds__(1024) void k_scan(const int* __restrict__ deg, int* __restrict__ cstart) {
    __shared__ int sd[1024];
    int t = threadIdx.x;
    int base = t * SCAN_K;
    int vals[SCAN_K];
    int s = 0;
    #pragma unroll
    for (int k = 0; k < SCAN_K; ++k) {
        int i = base + k;
        int v = (i < NN) ? deg[i] : 0;
        vals[k] = s; s += v;
    }
    sd[t] = s; __syncthreads();
    for (int off = 1; off < 1024; off <<= 1) {
        int add = (t >= off) ? sd[t - off] : 0;
        __syncthreads();
        sd[t] += add;
        __syncthreads();
    }
    int excl = (t == 0) ? 0 : sd[t - 1];
    #pragma unroll
    for (int k = 0; k < SCAN_K; ++k) {
        int i = base + k;
        if (i <= NN) cstart[i] = excl + vals[k];
    }
}

__global__ void k_fill(const int* __restrict__ ei, const int* __restrict__ cstart,
                       int* __restrict__ cursor, int* __restrict__ eidx) {
    int e = blockIdx.x * blockDim.x + threadIdx.x;
    if (e < NE) {
        int d = ei[NE + e];
        int pos = atomicAdd(&cursor[d], 1);
        eidx[cstart[d] + pos] = e;
    }
}

// ---------------- K2a: h = relu(agg + x@Wroot + bconv), thread per (node, o<16) ----------------
__global__ void k_h(const float* __restrict__ x, const float* __restrict__ Wroot,
                    const float* __restrict__ bconv, const float* __restrict__ msg,
                    const int* __restrict__ cstart, const int* __restrict__ eidx,
                    float* __restrict__ h) {
    int tid = blockIdx.x * blockDim.x + threadIdx.x;
    if (tid >= NN * 16) return;
    int n = tid >> 4, o = tid & 15;
    float acc = bconv[o];
    #pragma unroll
    for (int i = 0; i < 16; ++i) acc += x[n * 16 + i] * Wroot[i * 16 + o];
    int a0 = cstart[n], a1 = cstart[n + 1];
    for (int j = a0; j < a1; ++j) acc += msg[(long)eidx[j] * 16 + o];
    h[tid] = fmaxf(acc, 0.f);
}

// ---------------- K2b: hp = h@Wgat; sc_s/sc_d; wave per node, lane = feature ----------------
__global__ __launch_bounds__(256) void k_hp(const float* __restrict__ h, const float* __restrict__ Wgat,
                     const float* __restrict__ a_src, const float* __restrict__ a_dst,
                     float* __restrict__ hp, float* __restrict__ sc_s, float* __restrict__ sc_d) {
    int n = (blockIdx.x * blockDim.x + threadIdx.x) >> 6;
    int lane = threadIdx.x & 63;
    if (n >= NN) return;
    float acc = 0.f;
    #pragma unroll
    for (int i = 0; i < 16; ++i) acc += h[n * 16 + i] * Wgat[i * 64 + lane];
    hp[(long)n * 64 + lane] = acc;
    float ss = acc * a_src[lane];
    float sd = acc * a_dst[lane];
    #pragma unroll
    for (int off = 32; off; off >>= 1) {
        ss += __shfl_xor(ss, off);
        sd += __shfl_xor(sd, off);
    }
    if (lane == 0) { sc_s[n] = ss; sc_d[n] = sd; }
}

// ---------------- K3: GAT per-dst online softmax; wave per node, lane = feature ----------------
__global__ __launch_bounds__(256) void k_gat(const float* __restrict__ hp, const float* __restrict__ sc_s,
                     const float* __restrict__ sc_d, const int* __restrict__ ei,
                     const int* __restrict__ cstart, const int* __restrict__ eidx,
                     const float* __restrict__ bgat, float* __restrict__ gat) {
    int d = (blockIdx.x * blockDim.x + threadIdx.x) >> 6;
    int lane = threadIdx.x & 63;
    if (d >= NN) return;
    float sdv = sc_d[d];
    // self loop first
    float e0 = sc_s[d] + sdv;
    e0 = (e0 >= 0.f) ? e0 : 0.2f * e0;
    float mx = e0, l = 1.f;
    float acc = hp[(long)d * 64 + lane];
    int a0 = cstart[d], a1 = cstart[d + 1];
    for (int j = a0; j < a1; ++j) {
        int s = ei[eidx[j]]; // src of edge
        float sc = sc_s[s] + sdv;
        sc = (sc >= 0.f) ? sc : 0.2f * sc;
        float nm = fmaxf(mx, sc);
        float scale = __expf(mx - nm);
        float pc = __expf(sc - nm);
        l = l * scale + pc;
        acc = acc * scale + pc * hp[(long)s * 64 + lane];
        mx = nm;
    }
    float g = acc / l + bgat[lane];
    gat[(long)d * 64 + lane] = fmaxf(g, 0.f);
}

// ---------------- K4: mean pool per graph (batch_ids sorted -> binary search ranges) ----------------
static __device__ inline int lbound(const int* b, int key) {
    int lo = 0, hi = NN;
    while (lo < hi) { int mid = (lo + hi) >> 1; if (b[mid] < key) lo = mid + 1; else hi = mid; }
    return lo;
}
__global__ __launch_bounds__(256) void k_pool(const float* __restrict__ gat, const int* __restrict__ batch,
                      float* __restrict__ pooled) {
    int g = blockIdx.x;
    int r0 = lbound(batch, g);
    int r1 = lbound(batch, g + 1);
    int o = threadIdx.x & 63, gr = threadIdx.x >> 6;
    float part = 0.f;
    for (int r = r0 + gr; r < r1; r += 4) part += gat[(long)r * 64 + o];
    __shared__ float sd[256];
    sd[threadIdx.x] = part; __syncthreads();
    if (threadIdx.x < 64) {
        float tot = sd[o] + sd[64 + o] + sd[128 + o] + sd[192 + o];
        int cnt = r1 - r0;
        pooled[g * 64 + o] = tot / (float)(cnt > 0 ? cnt : 1);
    }
}

// ---------------- K5: MLP head, single block ----------------
__global__ __launch_bounds__(1024) void k_head(const float* __restrict__ pooled, const float* __restrict__ Wfc1,
                      const float* __restrict__ bfc1, const float* __restrict__ Wfc2,
                      const float* __restrict__ bfc2, float* __restrict__ out) {
    __shared__ float pl[NG * 64];
    __shared__ float zl[NG * 129];
    int t = threadIdx.x;
    for (int i = t; i < NG * 64; i += 1024) pl[i] = pooled[i];
    __syncthreads();
    int hcol = t & 127, gq = t >> 7; // gq 0..7, 8 graphs each
    float acc[8];
    #pragma unroll
    for (int g8 = 0; g8 < 8; ++g8) acc[g8] = bfc1[hcol];
    for (int i = 0; i < 64; ++i) {
        float wf = Wfc1[i * 128 + hcol];
        #pragma unroll
        for (int g8 = 0; g8 < 8; ++g8) acc[g8] += pl[(gq * 8 + g8) * 64 + i] * wf;
    }
    #pragma unroll
    for (int g8 = 0; g8 < 8; ++g8) zl[(gq * 8 + g8) * 129 + hcol] = fmaxf(acc[g8], 0.f);
    __syncthreads();
    if (t < NG) {
        float a = bfc2[0];
        for (int hh = 0; hh < 128; ++hh) a += zl[t * 129 + hh] * Wfc2[hh];
        out[t] = a;
    }
}

extern "C" void kernel_launch(void* const* d_in, const int* in_sizes, int n_in,
                              void* d_out, int out_size, void* d_ws, size_t ws_size,
                              hipStream_t stream) {
    (void)in_sizes; (void)n_in; (void)out_size; (void)ws_size;
    const float* x     = (const float*)d_in[0];
    const int*   ei    = (const int*)d_in[1];
    const float* ea    = (const float*)d_in[2];
    const int*   batch = (const int*)d_in[3];
    const float* We    = (const float*)d_in[4];
    const float* be    = (const float*)d_in[5];
    const float* Wroot = (const float*)d_in[6];
    const float* bconv = (const float*)d_in[7];
    const float* Wgat  = (const float*)d_in[8];
    const float* a_src = (const float*)d_in[9];
    const float* a_dst = (const float*)d_in[10];
    const float* bgat  = (const float*)d_in[11];
    const float* Wfc1  = (const float*)d_in[12];
    const float* bfc1  = (const float*)d_in[13];
    const float* Wfc2  = (const float*)d_in[14];
    const float* bfc2  = (const float*)d_in[15];

    char* w = (char*)d_ws;
    size_t o0 = 0;                          // deg      NN int
    size_t o1 = o0 + (size_t)NN * 4;        // cursor   NN int
    size_t o2 = o1 + (size_t)NN * 4;        // cstart   (NN+1) int
    size_t o3 = o2 + (size_t)(NN + 1) * 4;  // eidx     NE int
    size_t o4 = o3 + (size_t)NE * 4;        // msg      NE*16 f32
    size_t o5 = o4 + (size_t)NE * 16 * 4;   // h        NN*16 f32
    size_t o6 = o5 + (size_t)NN * 16 * 4;   // hp       NN*64 f32
    size_t o7 = o6 + (size_t)NN * 64 * 4;   // sc_s     NN f32
    size_t o8 = o7 + (size_t)NN * 4;        // sc_d     NN f32
    size_t o9 = o8 + (size_t)NN * 4;        // gat      NN*64 f32
    size_t o10 = o9 + (size_t)NN * 64 * 4;  // pooled   NG*64 f32

    int* deg      = (int*)(w + o0);
    int* cstart   = (int*)(w + o2);
    int* cursor   = (int*)(w + o1);
    int* eidx     = (int*)(w + o3);
    float* msg    = (float*)(w + o4);
    float* h      = (float*)(w + o5);
    float* hp     = (float*)(w + o6);
    float* sc_s   = (float*)(w + o7);
    float* sc_d   = (float*)(w + o8);
    float* gat    = (float*)(w + o9);
    float* pooled = (float*)(w + o10);

    hipMemsetAsync(w + o0, 0, (size_t)NN * 4 * 2, stream); // deg + cursor

    k_msg<<<640, 256, 0, stream>>>(x, ei, ea, We, be, msg);
    k_hist<<<(NE + 255) / 256, 256, 0, stream>>>(ei, deg);
    k_scan<<<1, 1024, 0, stream>>>(deg, cstart);
    k_fill<<<(NE + 255) / 256, 256, 0, stream>>>(ei, cstart, cursor, eidx);
    k_h<<<(NN * 16 + 255) / 256, 256, 0, stream>>>(x, Wroot, bconv, msg, cstart, eidx, h);
    k_hp<<<(NN + 3) / 4, 256, 0, stream>>>(h, Wgat, a_src, a_dst, hp, sc_s, sc_d);
    k_gat<<<(NN + 3) / 4, 256, 0, stream>>>(hp, sc_s, sc_d, ei, cstart, eidx, bgat, gat);
    k_pool<<<NG, 256, 0, stream>>>(gat, batch, pooled);
    k_head<<<1, 1024, 0, stream>>>(pooled, Wfc1, bfc1, Wfc2, bfc2, (float*)d_out);
}

// Round 2
// 268.858 us; speedup vs baseline: 1.1717x; 1.1717x over previous
//
#include <hip/hip_runtime.h>
#include <hip/hip_bf16.h>

#define NN 20000      // nodes
#define NE 320000     // edges
#define FE 32         // edge feature dim
#define DIN 16
#define DNN 16
#define DGAT 64
#define HID 128
#define NG 64         // graphs

using bf16x8 = __attribute__((ext_vector_type(8))) short;
using f32x4  = __attribute__((ext_vector_type(4))) float;

static __device__ inline short f2bf(float f) {
    unsigned u = __float_as_uint(f);
    unsigned r = u + 0x7FFFu + ((u >> 16) & 1u);
    return (short)(r >> 16);
}

union ABFrag {
    bf16x8 v;
    __hip_bfloat162 h2[4];
};

// ---------------- K1: NNConv messages via on-the-fly P @ We2 MFMA ----------------
// msg[e,o] = sum_{f,i} ea[e,f]*x[src[e],i]*We[f, i*16+o]  + sum_i x[src,i]*be[i*16+o]
// Also fused: dst-degree histogram (one atomicAdd per edge, done by quad==0 lanes).
__global__ __launch_bounds__(256) void k_msg(
    const float* __restrict__ x, const int* __restrict__ ei,
    const float* __restrict__ ea, const float* __restrict__ We,
    const float* __restrict__ be, float* __restrict__ msg,
    int* __restrict__ deg)
{
    const int lane = threadIdx.x & 63;
    const int wid  = threadIdx.x >> 6;
    const int m    = lane & 15;      // A-row (edge within tile) == B-col (n) == C col
    const int quad = lane >> 4;
    const int p    = quad >> 1;      // ea f-parity for this lane
    const int xh   = (quad & 1) * 8; // x half

    // Preload B fragments: B[k][n] = We2[k][n] = We[k>>4][(k&15)*16 + n]
    bf16x8 bfr[17];
    #pragma unroll
    for (int ks = 0; ks < 16; ++ks) {
        #pragma unroll
        for (int j = 0; j < 8; ++j) {
            int k = ks * 32 + quad * 8 + j;
            int f = k >> 4, i = k & 15;
            bfr[ks][j] = f2bf(We[f * 256 + i * 16 + m]);
        }
    }
    #pragma unroll
    for (int j = 0; j < 8; ++j) {
        int i = quad * 8 + j;
        bfr[16][j] = (quad < 2) ? f2bf(be[i * 16 + m]) : (short)0;
    }

    const int gw = blockIdx.x * 4 + wid;
    const int nw = gridDim.x * 4;
    const int* srcp = ei;            // first NE entries = src
    const int* dstp = ei + NE;       // next NE entries = dst

    for (int t = gw; t < NE / 16; t += nw) {
        const int e0 = t * 16;
        const int em = e0 + m;
        const int s  = srcp[em];

        // fused degree histogram: each edge counted once (quad 0 lanes)
        if (quad == 0) atomicAdd(&deg[dstp[em]], 1);

        float xf[8];
        {
            const float4* xr = (const float4*)(x + s * 16 + xh);
            float4 x0 = xr[0], x1 = xr[1];
            xf[0] = x0.x; xf[1] = x0.y; xf[2] = x0.z; xf[3] = x0.w;
            xf[4] = x1.x; xf[5] = x1.y; xf[6] = x1.z; xf[7] = x1.w;
        }
        float eav[16];
        {
            const float4* er = (const float4*)(ea + (long)em * 32);
            #pragma unroll
            for (int q = 0; q < 8; ++q) {
                float4 v = er[q];
                eav[2 * q]     = p ? v.y : v.x;
                eav[2 * q + 1] = p ? v.w : v.z;
            }
        }

        f32x4 acc = {0.f, 0.f, 0.f, 0.f};
        #pragma unroll
        for (int ks = 0; ks < 16; ++ks) {
            ABFrag a;
            float e = eav[ks];
            #pragma unroll
            for (int j = 0; j < 8; j += 2)
                a.h2[j >> 1] = __float22bfloat162_rn(make_float2(e * xf[j], e * xf[j + 1]));
            acc = __builtin_amdgcn_mfma_f32_16x16x32_bf16(a.v, bfr[ks], acc, 0, 0, 0);
        }
        { // bias K-step: P[e, 512+i] = x[src,i]
            ABFrag a;
            #pragma unroll
            for (int j = 0; j < 8; j += 2) {
                float f0 = (quad < 2) ? xf[j] : 0.f;
                float f1 = (quad < 2) ? xf[j + 1] : 0.f;
                a.h2[j >> 1] = __float22bfloat162_rn(make_float2(f0, f1));
            }
            acc = __builtin_amdgcn_mfma_f32_16x16x32_bf16(a.v, bfr[16], acc, 0, 0, 0);
        }
        // C/D: col = lane&15, row = quad*4 + reg
        #pragma unroll
        for (int r = 0; r < 4; ++r)
            msg[(long)(e0 + quad * 4 + r) * 16 + m] = acc[r];
    }
}

// ---------------- CSR build ----------------
#define SCAN_K 20
__global__ __launch_bounds__(1024) void k_scan(const int* __restrict__ deg, int* __restrict__ cstart) {
    __shared__ int sd[1024];
    int t = threadIdx.x;
    int base = t * SCAN_K;
    int vals[SCAN_K];
    int s = 0;
    #pragma unroll
    for (int k = 0; k < SCAN_K; ++k) {
        int i = base + k;
        int v = (i < NN) ? deg[i] : 0;
        vals[k] = s; s += v;
    }
    sd[t] = s; __syncthreads();
    for (int off = 1; off < 1024; off <<= 1) {
        int add = (t >= off) ? sd[t - off] : 0;
        __syncthreads();
        sd[t] += add;
        __syncthreads();
    }
    int excl = (t == 0) ? 0 : sd[t - 1];
    #pragma unroll
    for (int k = 0; k < SCAN_K; ++k) {
        int i = base + k;
        if (i <= NN) cstart[i] = excl + vals[k];
    }
}

__global__ void k_fill(const int* __restrict__ ei, const int* __restrict__ cstart,
                       int* __restrict__ cursor, int* __restrict__ eidx) {
    int e = blockIdx.x * blockDim.x + threadIdx.x;
    if (e < NE) {
        int d = ei[NE + e];
        int pos = atomicAdd(&cursor[d], 1);
        eidx[cstart[d] + pos] = e;
    }
}

// ---------------- K2a: h = relu(agg + x@Wroot + bconv), thread per (node, o<16) ----------------
__global__ void k_h(const float* __restrict__ x, const float* __restrict__ Wroot,
                    const float* __restrict__ bconv, const float* __restrict__ msg,
                    const int* __restrict__ cstart, const int* __restrict__ eidx,
                    float* __restrict__ h) {
    int tid = blockIdx.x * blockDim.x + threadIdx.x;
    if (tid >= NN * 16) return;
    int n = tid >> 4, o = tid & 15;
    float acc = bconv[o];
    #pragma unroll
    for (int i = 0; i < 16; ++i) acc += x[n * 16 + i] * Wroot[i * 16 + o];
    int a0 = cstart[n], a1 = cstart[n + 1];
    int j = a0;
    for (; j + 4 <= a1; j += 4) {
        int e0 = eidx[j], e1 = eidx[j + 1], e2 = eidx[j + 2], e3 = eidx[j + 3];
        float m0 = msg[(long)e0 * 16 + o];
        float m1 = msg[(long)e1 * 16 + o];
        float m2 = msg[(long)e2 * 16 + o];
        float m3 = msg[(long)e3 * 16 + o];
        acc += m0 + m1 + m2 + m3;
    }
    for (; j < a1; ++j) acc += msg[(long)eidx[j] * 16 + o];
    h[tid] = fmaxf(acc, 0.f);
}

// ---------------- K2b: hp = h@Wgat; sc_s/sc_d; wave per node, lane = feature ----------------
__global__ __launch_bounds__(256) void k_hp(const float* __restrict__ h, const float* __restrict__ Wgat,
                     const float* __restrict__ a_src, const float* __restrict__ a_dst,
                     float* __restrict__ hp, float* __restrict__ sc_s, float* __restrict__ sc_d) {
    int n = (blockIdx.x * blockDim.x + threadIdx.x) >> 6;
    int lane = threadIdx.x & 63;
    if (n >= NN) return;
    float acc = 0.f;
    #pragma unroll
    for (int i = 0; i < 16; ++i) acc += h[n * 16 + i] * Wgat[i * 64 + lane];
    hp[(long)n * 64 + lane] = acc;
    float ss = acc * a_src[lane];
    float sd = acc * a_dst[lane];
    #pragma unroll
    for (int off = 32; off; off >>= 1) {
        ss += __shfl_xor(ss, off);
        sd += __shfl_xor(sd, off);
    }
    if (lane == 0) { sc_s[n] = ss; sc_d[n] = sd; }
}

// ---------------- K3: GAT, wave per node, lane-parallel neighbor softmax ----------------
// Phase A: lanes handle neighbors in parallel (score, wave-reduce max & exp-sum).
// Phase B: broadcast (s_k, p_k) via shfl; accumulate p_k*hp[s_k] with independent
// coalesced loads (no dependent-chain serialization).
__global__ __launch_bounds__(256) void k_gat(const float* __restrict__ hp, const float* __restrict__ sc_s,
                     const float* __restrict__ sc_d, const int* __restrict__ ei,
                     const int* __restrict__ cstart, const int* __restrict__ eidx,
                     const float* __restrict__ bgat, float* __restrict__ gat) {
    int d = (blockIdx.x * blockDim.x + threadIdx.x) >> 6;
    int lane = threadIdx.x & 63;
    if (d >= NN) return;
    float sdv = sc_d[d];
    // self loop
    float e0 = sc_s[d] + sdv;
    e0 = (e0 >= 0.f) ? e0 : 0.2f * e0;
    float mx = e0, l = 1.f;
    float acc = hp[(long)d * 64 + lane];
    int a0 = cstart[d], a1 = cstart[d + 1];
    for (int base = a0; base < a1; base += 64) {
        int j = base + lane;
        bool valid = j < a1;
        int s = valid ? ei[eidx[j]] : 0;   // src of edge
        float sc = valid ? sc_s[s] + sdv : -1e30f;
        sc = (sc >= 0.f) ? sc : 0.2f * sc;
        float cm = sc;
        #pragma unroll
        for (int off = 32; off; off >>= 1) cm = fmaxf(cm, __shfl_xor(cm, off));
        float nm = fmaxf(mx, cm);
        float pj = valid ? __expf(sc - nm) : 0.f;
        float ps = pj;
        #pragma unroll
        for (int off = 32; off; off >>= 1) ps += __shfl_xor(ps, off);
        float scale = __expf(mx - nm);
        l = l * scale + ps;
        acc *= scale;
        mx = nm;
        int cnt = a1 - base; if (cnt > 64) cnt = 64;
        int k2 = 0;
        for (; k2 + 4 <= cnt; k2 += 4) {
            int   s0 = __shfl(s, k2),     s1 = __shfl(s, k2 + 1);
            int   s2 = __shfl(s, k2 + 2), s3 = __shfl(s, k2 + 3);
            float p0 = __shfl(pj, k2),     p1 = __shfl(pj, k2 + 1);
            float p2 = __shfl(pj, k2 + 2), p3 = __shfl(pj, k2 + 3);
            float h0 = hp[(long)s0 * 64 + lane];
            float h1 = hp[(long)s1 * 64 + lane];
            float h2 = hp[(long)s2 * 64 + lane];
            float h3 = hp[(long)s3 * 64 + lane];
            acc += p0 * h0 + p1 * h1 + p2 * h2 + p3 * h3;
        }
        for (; k2 < cnt; ++k2) {
            int sk = __shfl(s, k2);
            float pk = __shfl(pj, k2);
            acc += pk * hp[(long)sk * 64 + lane];
        }
    }
    float g = acc / l + bgat[lane];
    gat[(long)d * 64 + lane] = fmaxf(g, 0.f);
}

// ---------------- K4: mean pool per graph (batch_ids sorted -> binary search ranges) ----------------
static __device__ inline int lbound(const int* b, int key) {
    int lo = 0, hi = NN;
    while (lo < hi) { int mid = (lo + hi) >> 1; if (b[mid] < key) lo = mid + 1; else hi = mid; }
    return lo;
}
__global__ __launch_bounds__(256) void k_pool(const float* __restrict__ gat, const int* __restrict__ batch,
                      float* __restrict__ pooled) {
    int g = blockIdx.x;
    int r0 = lbound(batch, g);
    int r1 = lbound(batch, g + 1);
    int o = threadIdx.x & 63, gr = threadIdx.x >> 6;
    float part = 0.f;
    for (int r = r0 + gr; r < r1; r += 4) part += gat[(long)r * 64 + o];
    __shared__ float sd[256];
    sd[threadIdx.x] = part; __syncthreads();
    if (threadIdx.x < 64) {
        float tot = sd[o] + sd[64 + o] + sd[128 + o] + sd[192 + o];
        int cnt = r1 - r0;
        pooled[g * 64 + o] = tot / (float)(cnt > 0 ? cnt : 1);
    }
}

// ---------------- K5: MLP head, single block ----------------
__global__ __launch_bounds__(1024) void k_head(const float* __restrict__ pooled, const float* __restrict__ Wfc1,
                      const float* __restrict__ bfc1, const float* __restrict__ Wfc2,
                      const float* __restrict__ bfc2, float* __restrict__ out) {
    __shared__ float pl[NG * 64];
    __shared__ float zl[NG * 129];
    int t = threadIdx.x;
    for (int i = t; i < NG * 64; i += 1024) pl[i] = pooled[i];
    __syncthreads();
    int hcol = t & 127, gq = t >> 7; // gq 0..7, 8 graphs each
    float acc[8];
    #pragma unroll
    for (int g8 = 0; g8 < 8; ++g8) acc[g8] = bfc1[hcol];
    for (int i = 0; i < 64; ++i) {
        float wf = Wfc1[i * 128 + hcol];
        #pragma unroll
        for (int g8 = 0; g8 < 8; ++g8) acc[g8] += pl[(gq * 8 + g8) * 64 + i] * wf;
    }
    #pragma unroll
    for (int g8 = 0; g8 < 8; ++g8) zl[(gq * 8 + g8) * 129 + hcol] = fmaxf(acc[g8], 0.f);
    __syncthreads();
    if (t < NG) {
        float a = bfc2[0];
        for (int hh = 0; hh < 128; ++hh) a += zl[t * 129 + hh] * Wfc2[hh];
        out[t] = a;
    }
}

extern "C" void kernel_launch(void* const* d_in, const int* in_sizes, int n_in,
                              void* d_out, int out_size, void* d_ws, size_t ws_size,
                              hipStream_t stream) {
    (void)in_sizes; (void)n_in; (void)out_size; (void)ws_size;
    const float* x     = (const float*)d_in[0];
    const int*   ei    = (const int*)d_in[1];
    const float* ea    = (const float*)d_in[2];
    const int*   batch = (const int*)d_in[3];
    const float* We    = (const float*)d_in[4];
    const float* be    = (const float*)d_in[5];
    const float* Wroot = (const float*)d_in[6];
    const float* bconv = (const float*)d_in[7];
    const float* Wgat  = (const float*)d_in[8];
    const float* a_src = (const float*)d_in[9];
    const float* a_dst = (const float*)d_in[10];
    const float* bgat  = (const float*)d_in[11];
    const float* Wfc1  = (const float*)d_in[12];
    const float* bfc1  = (const float*)d_in[13];
    const float* Wfc2  = (const float*)d_in[14];
    const float* bfc2  = (const float*)d_in[15];

    char* w = (char*)d_ws;
    size_t o0 = 0;                          // deg      NN int
    size_t o1 = o0 + (size_t)NN * 4;        // cursor   NN int
    size_t o2 = o1 + (size_t)NN * 4;        // cstart   (NN+1) int
    size_t o3 = o2 + (size_t)(NN + 1) * 4;  // eidx     NE int
    size_t o4 = o3 + (size_t)NE * 4;        // msg      NE*16 f32
    size_t o5 = o4 + (size_t)NE * 16 * 4;   // h        NN*16 f32
    size_t o6 = o5 + (size_t)NN * 16 * 4;   // hp       NN*64 f32
    size_t o7 = o6 + (size_t)NN * 64 * 4;   // sc_s     NN f32
    size_t o8 = o7 + (size_t)NN * 4;        // sc_d     NN f32
    size_t o9 = o8 + (size_t)NN * 4;        // gat      NN*64 f32
    size_t o10 = o9 + (size_t)NN * 64 * 4;  // pooled   NG*64 f32

    int* deg      = (int*)(w + o0);
    int* cursor   = (int*)(w + o1);
    int* cstart   = (int*)(w + o2);
    int* eidx     = (int*)(w + o3);
    float* msg    = (float*)(w + o4);
    float* h      = (float*)(w + o5);
    float* hp     = (float*)(w + o6);
    float* sc_s   = (float*)(w + o7);
    float* sc_d   = (float*)(w + o8);
    float* gat    = (float*)(w + o9);
    float* pooled = (float*)(w + o10);

    hipMemsetAsync(w + o0, 0, (size_t)NN * 4 * 2, stream); // deg + cursor

    k_msg<<<640, 256, 0, stream>>>(x, ei, ea, We, be, msg, deg);
    k_scan<<<1, 1024, 0, stream>>>(deg, cstart);
    k_fill<<<(NE + 255) / 256, 256, 0, stream>>>(ei, cstart, cursor, eidx);
    k_h<<<(NN * 16 + 255) / 256, 256, 0, stream>>>(x, Wroot, bconv, msg, cstart, eidx, h);
    k_hp<<<(NN + 3) / 4, 256, 0, stream>>>(h, Wgat, a_src, a_dst, hp, sc_s, sc_d);
    k_gat<<<(NN + 3) / 4, 256, 0, stream>>>(hp, sc_s, sc_d, ei, cstart, eidx, bgat, gat);
    k_pool<<<NG, 256, 0, stream>>>(gat, batch, pooled);
    k_head<<<1, 1024, 0, stream>>>(pooled, Wfc1, bfc1, Wfc2, bfc2, (float*)d_out);
}

// Round 3
// 262.287 us; speedup vs baseline: 1.2011x; 1.0251x over previous
//
#include <hip/hip_runtime.h>
#include <hip/hip_bf16.h>

#define NN 20000      // nodes
#define NE 320000     // edges
#define FE 32         // edge feature dim
#define DIN 16
#define DNN 16
#define DGAT 64
#define HID 128
#define NG 64         // graphs

using bf16x8 = __attribute__((ext_vector_type(8))) short;
using f32x4  = __attribute__((ext_vector_type(4))) float;

static __device__ inline short f2bf(float f) {
    unsigned u = __float_as_uint(f);
    unsigned r = u + 0x7FFFu + ((u >> 16) & 1u);
    return (short)(r >> 16);
}

union ABFrag {
    bf16x8 v;
    __hip_bfloat162 h2[4];
};

// ---------------- K0: init — zero deg+cursor AND build bf16-transposed We2t ----------------
// We2t[m*544 + k]: k<512 -> bf16(We[k>>4][(k&15)*16+m]); k in [512,528) -> bf16(be[(k-512)*16+m]);
// k in [528,544) -> 0 (kills the A-garbage in the bias MFMA k-step for quads 2,3).
__global__ void k_init(const float* __restrict__ We, const float* __restrict__ be,
                       int* __restrict__ degcur, short* __restrict__ we2t) {
    int tid = blockIdx.x * blockDim.x + threadIdx.x;
    if (tid < 2 * NN) degcur[tid] = 0;
    if (tid < 16 * 544) {
        int k = tid % 544, m = tid / 544;
        float v;
        if (k < 512)      { int f = k >> 4, i = k & 15; v = We[f * 256 + i * 16 + m]; }
        else if (k < 528) { int i = k - 512; v = be[i * 16 + m]; }
        else              v = 0.f;
        we2t[tid] = f2bf(v);
    }
}

// ---------------- K1: NNConv messages via on-the-fly P @ We2 MFMA ----------------
// msg[e,o] = sum_{f,i} ea[e,f]*x[src[e],i]*We[f, i*16+o]  + sum_i x[src,i]*be[i*16+o]
// Fused: dst-degree histogram. 2 tiles (of 16 edges) per wave, 10000 waves.
__global__ __launch_bounds__(256) void k_msg(
    const float* __restrict__ x, const int* __restrict__ ei,
    const float* __restrict__ ea, const short* __restrict__ we2t,
    float* __restrict__ msg, int* __restrict__ deg)
{
    const int lane = threadIdx.x & 63;
    const int wid  = threadIdx.x >> 6;
    const int m    = lane & 15;      // A-row (edge within tile) == B-col (n) == C col
    const int quad = lane >> 4;
    const int p    = quad >> 1;      // ea f-parity for this lane
    const int xh   = (quad & 1) * 8; // x half

    // Preload B fragments from precomputed bf16 table: 17 aligned 16B loads.
    const short* wt = we2t + m * 544 + quad * 8;
    bf16x8 bfr[17];
    #pragma unroll
    for (int ks = 0; ks < 17; ++ks)
        bfr[ks] = *(const bf16x8*)(wt + ks * 32);

    const int* srcp = ei;            // first NE entries = src
    const int* dstp = ei + NE;       // next NE entries = dst

    const int t0 = (blockIdx.x * 4 + wid) * 2;
    #pragma unroll
    for (int t = t0; t < t0 + 2; ++t) {
        const int e0 = t * 16;
        const int em = e0 + m;
        const int s  = srcp[em];

        // fused degree histogram: each edge counted once (quad 0 lanes)
        if (quad == 0) atomicAdd(&deg[dstp[em]], 1);

        float xf[8];
        {
            const float4* xr = (const float4*)(x + s * 16 + xh);
            float4 x0 = xr[0], x1 = xr[1];
            xf[0] = x0.x; xf[1] = x0.y; xf[2] = x0.z; xf[3] = x0.w;
            xf[4] = x1.x; xf[5] = x1.y; xf[6] = x1.z; xf[7] = x1.w;
        }
        float eav[16];
        {
            const float4* er = (const float4*)(ea + (long)em * 32);
            #pragma unroll
            for (int q = 0; q < 8; ++q) {
                float4 v = er[q];
                eav[2 * q]     = p ? v.y : v.x;
                eav[2 * q + 1] = p ? v.w : v.z;
            }
        }

        f32x4 acc = {0.f, 0.f, 0.f, 0.f};
        #pragma unroll
        for (int ks = 0; ks < 16; ++ks) {
            ABFrag a;
            float e = eav[ks];
            #pragma unroll
            for (int j = 0; j < 8; j += 2)
                a.h2[j >> 1] = __float22bfloat162_rn(make_float2(e * xf[j], e * xf[j + 1]));
            acc = __builtin_amdgcn_mfma_f32_16x16x32_bf16(a.v, bfr[ks], acc, 0, 0, 0);
        }
        { // bias K-step: B rows >=528 are zero, so A needs no masking
            ABFrag a;
            #pragma unroll
            for (int j = 0; j < 8; j += 2)
                a.h2[j >> 1] = __float22bfloat162_rn(make_float2(xf[j], xf[j + 1]));
            acc = __builtin_amdgcn_mfma_f32_16x16x32_bf16(a.v, bfr[16], acc, 0, 0, 0);
        }
        // C/D: col = lane&15, row = quad*4 + reg
        #pragma unroll
        for (int r = 0; r < 4; ++r)
            msg[(long)(e0 + quad * 4 + r) * 16 + m] = acc[r];
    }
}

// ---------------- CSR build ----------------
#define SCAN_K 20
__global__ __launch_bounds__(1024) void k_scan(const int* __restrict__ deg, int* __restrict__ cstart) {
    __shared__ int sd[1024];
    int t = threadIdx.x;
    int base = t * SCAN_K;
    int vals[SCAN_K];
    int s = 0;
    #pragma unroll
    for (int k = 0; k < SCAN_K; ++k) {
        int i = base + k;
        int v = (i < NN) ? deg[i] : 0;
        vals[k] = s; s += v;
    }
    sd[t] = s; __syncthreads();
    for (int off = 1; off < 1024; off <<= 1) {
        int add = (t >= off) ? sd[t - off] : 0;
        __syncthreads();
        sd[t] += add;
        __syncthreads();
    }
    int excl = (t == 0) ? 0 : sd[t - 1];
    #pragma unroll
    for (int k = 0; k < SCAN_K; ++k) {
        int i = base + k;
        if (i <= NN) cstart[i] = excl + vals[k];
    }
}

__global__ void k_fill(const int* __restrict__ ei, const int* __restrict__ cstart,
                       int* __restrict__ cursor, int* __restrict__ eidx) {
    int e = blockIdx.x * blockDim.x + threadIdx.x;
    if (e < NE) {
        int d = ei[NE + e];
        int pos = atomicAdd(&cursor[d], 1);
        eidx[cstart[d] + pos] = e;
    }
}

// ---------------- K2a: h = relu(agg + x@Wroot + bconv), thread per (node, o<16) ----------------
__global__ void k_h(const float* __restrict__ x, const float* __restrict__ Wroot,
                    const float* __restrict__ bconv, const float* __restrict__ msg,
                    const int* __restrict__ cstart, const int* __restrict__ eidx,
                    float* __restrict__ h) {
    int tid = blockIdx.x * blockDim.x + threadIdx.x;
    if (tid >= NN * 16) return;
    int n = tid >> 4, o = tid & 15;
    float acc = bconv[o];
    #pragma unroll
    for (int i = 0; i < 16; ++i) acc += x[n * 16 + i] * Wroot[i * 16 + o];
    int a0 = cstart[n], a1 = cstart[n + 1];
    int j = a0;
    for (; j + 4 <= a1; j += 4) {
        int e0 = eidx[j], e1 = eidx[j + 1], e2 = eidx[j + 2], e3 = eidx[j + 3];
        float m0 = msg[(long)e0 * 16 + o];
        float m1 = msg[(long)e1 * 16 + o];
        float m2 = msg[(long)e2 * 16 + o];
        float m3 = msg[(long)e3 * 16 + o];
        acc += m0 + m1 + m2 + m3;
    }
    for (; j < a1; ++j) acc += msg[(long)eidx[j] * 16 + o];
    h[tid] = fmaxf(acc, 0.f);
}

// ---------------- K2b: hp = h@Wgat; sc_s/sc_d; wave per node, lane = feature ----------------
__global__ __launch_bounds__(256) void k_hp(const float* __restrict__ h, const float* __restrict__ Wgat,
                     const float* __restrict__ a_src, const float* __restrict__ a_dst,
                     float* __restrict__ hp, float* __restrict__ sc_s, float* __restrict__ sc_d) {
    int n = (blockIdx.x * blockDim.x + threadIdx.x) >> 6;
    int lane = threadIdx.x & 63;
    if (n >= NN) return;
    float acc = 0.f;
    #pragma unroll
    for (int i = 0; i < 16; ++i) acc += h[n * 16 + i] * Wgat[i * 64 + lane];
    hp[(long)n * 64 + lane] = acc;
    float ss = acc * a_src[lane];
    float sd = acc * a_dst[lane];
    #pragma unroll
    for (int off = 32; off; off >>= 1) {
        ss += __shfl_xor(ss, off);
        sd += __shfl_xor(sd, off);
    }
    if (lane == 0) { sc_s[n] = ss; sc_d[n] = sd; }
}

// ---------------- K3: GAT, wave per node, lane-parallel neighbor softmax ----------------
__global__ __launch_bounds__(256) void k_gat(const float* __restrict__ hp, const float* __restrict__ sc_s,
                     const float* __restrict__ sc_d, const int* __restrict__ ei,
                     const int* __restrict__ cstart, const int* __restrict__ eidx,
                     const float* __restrict__ bgat, float* __restrict__ gat) {
    int d = (blockIdx.x * blockDim.x + threadIdx.x) >> 6;
    int lane = threadIdx.x & 63;
    if (d >= NN) return;
    float sdv = sc_d[d];
    // self loop
    float e0 = sc_s[d] + sdv;
    e0 = (e0 >= 0.f) ? e0 : 0.2f * e0;
    float mx = e0, l = 1.f;
    float acc = hp[(long)d * 64 + lane];
    int a0 = cstart[d], a1 = cstart[d + 1];
    for (int base = a0; base < a1; base += 64) {
        int j = base + lane;
        bool valid = j < a1;
        int s = valid ? ei[eidx[j]] : 0;   // src of edge
        float sc = valid ? sc_s[s] + sdv : -1e30f;
        sc = (sc >= 0.f) ? sc : 0.2f * sc;
        float cm = sc;
        #pragma unroll
        for (int off = 32; off; off >>= 1) cm = fmaxf(cm, __shfl_xor(cm, off));
        float nm = fmaxf(mx, cm);
        float pj = valid ? __expf(sc - nm) : 0.f;
        float ps = pj;
        #pragma unroll
        for (int off = 32; off; off >>= 1) ps += __shfl_xor(ps, off);
        float scale = __expf(mx - nm);
        l = l * scale + ps;
        acc *= scale;
        mx = nm;
        int cnt = a1 - base; if (cnt > 64) cnt = 64;
        int k2 = 0;
        for (; k2 + 4 <= cnt; k2 += 4) {
            int   s0 = __shfl(s, k2),     s1 = __shfl(s, k2 + 1);
            int   s2 = __shfl(s, k2 + 2), s3 = __shfl(s, k2 + 3);
            float p0 = __shfl(pj, k2),     p1 = __shfl(pj, k2 + 1);
            float p2 = __shfl(pj, k2 + 2), p3 = __shfl(pj, k2 + 3);
            float h0 = hp[(long)s0 * 64 + lane];
            float h1 = hp[(long)s1 * 64 + lane];
            float h2 = hp[(long)s2 * 64 + lane];
            float h3 = hp[(long)s3 * 64 + lane];
            acc += p0 * h0 + p1 * h1 + p2 * h2 + p3 * h3;
        }
        for (; k2 < cnt; ++k2) {
            int sk = __shfl(s, k2);
            float pk = __shfl(pj, k2);
            acc += pk * hp[(long)sk * 64 + lane];
        }
    }
    float g = acc / l + bgat[lane];
    gat[(long)d * 64 + lane] = fmaxf(g, 0.f);
}

// ---------------- K4: mean pool per graph (batch_ids sorted -> binary search ranges) ----------------
static __device__ inline int lbound(const int* b, int key) {
    int lo = 0, hi = NN;
    while (lo < hi) { int mid = (lo + hi) >> 1; if (b[mid] < key) lo = mid + 1; else hi = mid; }
    return lo;
}
__global__ __launch_bounds__(256) void k_pool(const float* __restrict__ gat, const int* __restrict__ batch,
                      float* __restrict__ pooled) {
    int g = blockIdx.x;
    int r0 = lbound(batch, g);
    int r1 = lbound(batch, g + 1);
    int o = threadIdx.x & 63, gr = threadIdx.x >> 6;
    float part = 0.f;
    for (int r = r0 + gr; r < r1; r += 4) part += gat[(long)r * 64 + o];
    __shared__ float sd[256];
    sd[threadIdx.x] = part; __syncthreads();
    if (threadIdx.x < 64) {
        float tot = sd[o] + sd[64 + o] + sd[128 + o] + sd[192 + o];
        int cnt = r1 - r0;
        pooled[g * 64 + o] = tot / (float)(cnt > 0 ? cnt : 1);
    }
}

// ---------------- K5: MLP head, single block ----------------
__global__ __launch_bounds__(1024) void k_head(const float* __restrict__ pooled, const float* __restrict__ Wfc1,
                      const float* __restrict__ bfc1, const float* __restrict__ Wfc2,
                      const float* __restrict__ bfc2, float* __restrict__ out) {
    __shared__ float pl[NG * 64];
    __shared__ float zl[NG * 129];
    int t = threadIdx.x;
    for (int i = t; i < NG * 64; i += 1024) pl[i] = pooled[i];
    __syncthreads();
    int hcol = t & 127, gq = t >> 7; // gq 0..7, 8 graphs each
    float acc[8];
    #pragma unroll
    for (int g8 = 0; g8 < 8; ++g8) acc[g8] = bfc1[hcol];
    for (int i = 0; i < 64; ++i) {
        float wf = Wfc1[i * 128 + hcol];
        #pragma unroll
        for (int g8 = 0; g8 < 8; ++g8) acc[g8] += pl[(gq * 8 + g8) * 64 + i] * wf;
    }
    #pragma unroll
    for (int g8 = 0; g8 < 8; ++g8) zl[(gq * 8 + g8) * 129 + hcol] = fmaxf(acc[g8], 0.f);
    __syncthreads();
    if (t < NG) {
        float a = bfc2[0];
        for (int hh = 0; hh < 128; ++hh) a += zl[t * 129 + hh] * Wfc2[hh];
        out[t] = a;
    }
}

extern "C" void kernel_launch(void* const* d_in, const int* in_sizes, int n_in,
                              void* d_out, int out_size, void* d_ws, size_t ws_size,
                              hipStream_t stream) {
    (void)in_sizes; (void)n_in; (void)out_size; (void)ws_size;
    const float* x     = (const float*)d_in[0];
    const int*   ei    = (const int*)d_in[1];
    const float* ea    = (const float*)d_in[2];
    const int*   batch = (const int*)d_in[3];
    const float* We    = (const float*)d_in[4];
    const float* be    = (const float*)d_in[5];
    const float* Wroot = (const float*)d_in[6];
    const float* bconv = (const float*)d_in[7];
    const float* Wgat  = (const float*)d_in[8];
    const float* a_src = (const float*)d_in[9];
    const float* a_dst = (const float*)d_in[10];
    const float* bgat  = (const float*)d_in[11];
    const float* Wfc1  = (const float*)d_in[12];
    const float* bfc1  = (const float*)d_in[13];
    const float* Wfc2  = (const float*)d_in[14];
    const float* bfc2  = (const float*)d_in[15];

    char* w = (char*)d_ws;
    size_t o0 = 0;                          // deg      NN int
    size_t o1 = o0 + (size_t)NN * 4;        // cursor   NN int   (contiguous after deg)
    size_t o2 = o1 + (size_t)NN * 4;        // cstart   (NN+1) int
    size_t o3 = o2 + (size_t)(NN + 1) * 4;  // eidx     NE int
    size_t o4 = o3 + (size_t)NE * 4;        // msg      NE*16 f32
    size_t o5 = o4 + (size_t)NE * 16 * 4;   // h        NN*16 f32
    size_t o6 = o5 + (size_t)NN * 16 * 4;   // hp       NN*64 f32
    size_t o7 = o6 + (size_t)NN * 64 * 4;   // sc_s     NN f32
    size_t o8 = o7 + (size_t)NN * 4;        // sc_d     NN f32
    size_t o9 = o8 + (size_t)NN * 4;        // gat      NN*64 f32
    size_t o10 = o9 + (size_t)NN * 64 * 4;  // pooled   NG*64 f32
    size_t o11 = o10 + (size_t)NG * 64 * 4; // we2t     16*544 bf16
    o11 = (o11 + 15) & ~(size_t)15;

    int* degcur   = (int*)(w + o0);
    int* deg      = (int*)(w + o0);
    int* cursor   = (int*)(w + o1);
    int* cstart   = (int*)(w + o2);
    int* eidx     = (int*)(w + o3);
    float* msg    = (float*)(w + o4);
    float* h      = (float*)(w + o5);
    float* hp     = (float*)(w + o6);
    float* sc_s   = (float*)(w + o7);
    float* sc_d   = (float*)(w + o8);
    float* gat    = (float*)(w + o9);
    float* pooled = (float*)(w + o10);
    short* we2t   = (short*)(w + o11);

    k_init<<<(2 * NN + 255) / 256, 256, 0, stream>>>(We, be, degcur, we2t);
    k_msg<<<2500, 256, 0, stream>>>(x, ei, ea, we2t, msg, deg);
    k_scan<<<1, 1024, 0, stream>>>(deg, cstart);
    k_fill<<<(NE + 255) / 256, 256, 0, stream>>>(ei, cstart, cursor, eidx);
    k_h<<<(NN * 16 + 255) / 256, 256, 0, stream>>>(x, Wroot, bconv, msg, cstart, eidx, h);
    k_hp<<<(NN + 3) / 4, 256, 0, stream>>>(h, Wgat, a_src, a_dst, hp, sc_s, sc_d);
    k_gat<<<(NN + 3) / 4, 256, 0, stream>>>(hp, sc_s, sc_d, ei, cstart, eidx, bgat, gat);
    k_pool<<<NG, 256, 0, stream>>>(gat, batch, pooled);
    k_head<<<1, 1024, 0, stream>>>(pooled, Wfc1, bfc1, Wfc2, bfc2, (float*)d_out);
}

// Round 5
// 255.389 us; speedup vs baseline: 1.2335x; 1.0270x over previous
//
#include <hip/hip_runtime.h>
#include <hip/hip_bf16.h>
#include <hip/hip_fp16.h>

#define NN 20000      // nodes
#define NE 320000     // edges
#define FE 32         // edge feature dim
#define DIN 16
#define DNN 16
#define DGAT 64
#define HID 128
#define NG 64         // graphs

using f16x8 = __attribute__((ext_vector_type(8))) _Float16;
using f32x4 = __attribute__((ext_vector_type(4))) float;

union AFrag {
    f16x8 v;
    __half2 h2[4];
};

// ---------------- K0: init — zero deg+cursor AND build f16-transposed We2t ----------------
// we2t[m*544 + k]: k<512 -> f16(We[k>>4][(k&15)*16+m]); k in [512,528) -> f16(be[(k-512)*16+m]);
// k in [528,544) -> 0 (so the bias MFMA k-step needs no A-masking for quads 2,3).
__global__ void k_init(const float* __restrict__ We, const float* __restrict__ be,
                       int* __restrict__ degcur, __half* __restrict__ we2t) {
    int tid = blockIdx.x * blockDim.x + threadIdx.x;
    if (tid < 2 * NN) degcur[tid] = 0;
    if (tid < 16 * 544) {
        int k = tid % 544, m = tid / 544;
        float v;
        if (k < 512)      { int f = k >> 4, i = k & 15; v = We[f * 256 + i * 16 + m]; }
        else if (k < 528) { int i = k - 512; v = be[i * 16 + m]; }
        else              v = 0.f;
        we2t[tid] = __float2half(v);
    }
}

// ---------------- CSR build: hist -> scan -> fill(pos_e, esrc) ----------------
__global__ void k_hist(const int* __restrict__ ei, int* __restrict__ deg) {
    int e = blockIdx.x * blockDim.x + threadIdx.x;
    if (e < NE) atomicAdd(&deg[ei[NE + e]], 1);
}

#define SCAN_K 20
__global__ __launch_bounds__(1024) void k_scan(const int* __restrict__ deg, int* __restrict__ cstart) {
    __shared__ int sd[1024];
    int t = threadIdx.x;
    int base = t * SCAN_K;
    int vals[SCAN_K];
    int s = 0;
    #pragma unroll
    for (int k = 0; k < SCAN_K; ++k) {
        int i = base + k;
        int v = (i < NN) ? deg[i] : 0;
        vals[k] = s; s += v;
    }
    sd[t] = s; __syncthreads();
    for (int off = 1; off < 1024; off <<= 1) {
        int add = (t >= off) ? sd[t - off] : 0;
        __syncthreads();
        sd[t] += add;
        __syncthreads();
    }
    int excl = (t == 0) ? 0 : sd[t - 1];
    #pragma unroll
    for (int k = 0; k < SCAN_K; ++k) {
        int i = base + k;
        if (i <= NN) cstart[i] = excl + vals[k];
    }
}

__global__ void k_fill(const int* __restrict__ ei, const int* __restrict__ cstart,
                       int* __restrict__ cursor, int* __restrict__ pos_e, int* __restrict__ esrc) {
    int e = blockIdx.x * blockDim.x + threadIdx.x;
    if (e < NE) {
        int d = ei[NE + e];
        int p = atomicAdd(&cursor[d], 1);
        int c = cstart[d] + p;
        pos_e[e] = c;
        esrc[c] = ei[e];
    }
}

// ---------------- K1: NNConv messages, fp16 MFMA, CSR-ordered output ----------------
// msg_csr[pos_e[e], o] = sum_{f,i} ea[e,f]*x[src[e],i]*We[f,i*16+o] + sum_i x[src,i]*be[i*16+o]
__global__ __launch_bounds__(256) void k_msg(
    const float* __restrict__ x, const int* __restrict__ ei,
    const float* __restrict__ ea, const __half* __restrict__ we2t,
    const int* __restrict__ pos_e, float* __restrict__ msg)
{
    const int lane = threadIdx.x & 63;
    const int wid  = threadIdx.x >> 6;
    const int m    = lane & 15;      // A-row (edge within tile) == C col
    const int quad = lane >> 4;
    const int p    = quad >> 1;      // ea f-parity for this lane
    const int xh   = (quad & 1) * 8; // x half

    // B fragments: 17 aligned 16B loads from precomputed f16 table.
    const __half* wt = we2t + m * 544 + quad * 8;
    f16x8 bfr[17];
    #pragma unroll
    for (int ks = 0; ks < 17; ++ks)
        bfr[ks] = *(const f16x8*)(wt + ks * 32);

    const int t0  = (blockIdx.x * 4 + wid) * 2;
    const int e0A = t0 * 16, e0B = e0A + 16;

    // ---- hoist ALL loads for both tiles (issue as one batch) ----
    const int sA = ei[e0A + m];
    const int sB = ei[e0B + m];
    const int4 posA = *(const int4*)(pos_e + e0A + quad * 4);
    const int4 posB = *(const int4*)(pos_e + e0B + quad * 4);
    float4 evA[8], evB[8];
    {
        const float4* erA = (const float4*)(ea + (long)(e0A + m) * 32);
        const float4* erB = (const float4*)(ea + (long)(e0B + m) * 32);
        #pragma unroll
        for (int q = 0; q < 8; ++q) { evA[q] = erA[q]; evB[q] = erB[q]; }
    }
    float xfA[8], xfB[8];
    {
        const float4* xrA = (const float4*)(x + sA * 16 + xh);
        const float4* xrB = (const float4*)(x + sB * 16 + xh);
        float4 a0 = xrA[0], a1 = xrA[1], b0 = xrB[0], b1 = xrB[1];
        xfA[0]=a0.x; xfA[1]=a0.y; xfA[2]=a0.z; xfA[3]=a0.w;
        xfA[4]=a1.x; xfA[5]=a1.y; xfA[6]=a1.z; xfA[7]=a1.w;
        xfB[0]=b0.x; xfB[1]=b0.y; xfB[2]=b0.z; xfB[3]=b0.w;
        xfB[4]=b1.x; xfB[5]=b1.y; xfB[6]=b1.z; xfB[7]=b1.w;
    }

    // ---- tile A ----
    {
        float eav[16];
        #pragma unroll
        for (int q = 0; q < 8; ++q) {
            eav[2*q]   = p ? evA[q].y : evA[q].x;
            eav[2*q+1] = p ? evA[q].w : evA[q].z;
        }
        __half2 xp[4];
        #pragma unroll
        for (int j = 0; j < 4; ++j)
            xp[j] = __float22half2_rn(make_float2(xfA[2*j], xfA[2*j+1]));
        f32x4 acc = {0.f, 0.f, 0.f, 0.f};
        #pragma unroll
        for (int ks = 0; ks < 16; ++ks) {
            __half2 eh = __float2half2_rn(eav[ks]);
            AFrag a;
            #pragma unroll
            for (int j = 0; j < 4; ++j) a.h2[j] = __hmul2(eh, xp[j]);
            acc = __builtin_amdgcn_mfma_f32_16x16x32_f16(a.v, bfr[ks], acc, 0, 0, 0);
        }
        {
            AFrag a;
            #pragma unroll
            for (int j = 0; j < 4; ++j) a.h2[j] = xp[j];
            acc = __builtin_amdgcn_mfma_f32_16x16x32_f16(a.v, bfr[16], acc, 0, 0, 0);
        }
        msg[(long)posA.x * 16 + m] = acc[0];
        msg[(long)posA.y * 16 + m] = acc[1];
        msg[(long)posA.z * 16 + m] = acc[2];
        msg[(long)posA.w * 16 + m] = acc[3];
    }
    // ---- tile B ----
    {
        float eav[16];
        #pragma unroll
        for (int q = 0; q < 8; ++q) {
            eav[2*q]   = p ? evB[q].y : evB[q].x;
            eav[2*q+1] = p ? evB[q].w : evB[q].z;
        }
        __half2 xp[4];
        #pragma unroll
        for (int j = 0; j < 4; ++j)
            xp[j] = __float22half2_rn(make_float2(xfB[2*j], xfB[2*j+1]));
        f32x4 acc = {0.f, 0.f, 0.f, 0.f};
        #pragma unroll
        for (int ks = 0; ks < 16; ++ks) {
            __half2 eh = __float2half2_rn(eav[ks]);
            AFrag a;
            #pragma unroll
            for (int j = 0; j < 4; ++j) a.h2[j] = __hmul2(eh, xp[j]);
            acc = __builtin_amdgcn_mfma_f32_16x16x32_f16(a.v, bfr[ks], acc, 0, 0, 0);
        }
        {
            AFrag a;
            #pragma unroll
            for (int j = 0; j < 4; ++j) a.h2[j] = xp[j];
            acc = __builtin_amdgcn_mfma_f32_16x16x32_f16(a.v, bfr[16], acc, 0, 0, 0);
        }
        msg[(long)posB.x * 16 + m] = acc[0];
        msg[(long)posB.y * 16 + m] = acc[1];
        msg[(long)posB.z * 16 + m] = acc[2];
        msg[(long)posB.w * 16 + m] = acc[3];
    }
}

// ---------------- K2: fused NNConv-finish + GAT projection; wave per node ----------------
// h = relu(sum(msg rows) + x@Wroot + bconv); hp = h@Wgat; sc_s/sc_d; hpb = f16(hp).
__global__ __launch_bounds__(256) void k_node(
    const float* __restrict__ x, const float* __restrict__ Wroot,
    const float* __restrict__ bconv, const float* __restrict__ msg,
    const int* __restrict__ cstart, const float* __restrict__ Wgat,
    const float* __restrict__ a_src, const float* __restrict__ a_dst,
    float* __restrict__ hp, __half* __restrict__ hpb,
    float* __restrict__ sc_s, float* __restrict__ sc_d)
{
    int n = (blockIdx.x * blockDim.x + threadIdx.x) >> 6;
    int lane = threadIdx.x & 63;
    if (n >= NN) return;
    int o = lane & 15, g4 = lane >> 4;
    int a0 = cstart[n], a1 = cstart[n + 1];
    float part = 0.f;
    for (int j = a0 + g4; j < a1; j += 4) part += msg[(long)j * 16 + o];  // contiguous rows
    part += __shfl_xor(part, 16);
    part += __shfl_xor(part, 32);
    float xv = x[n * 16 + o];
    float acc = bconv[o] + part;
    #pragma unroll
    for (int i = 0; i < 16; ++i) acc += __shfl(xv, i) * Wroot[i * 16 + o];
    float hv = fmaxf(acc, 0.f);                  // replicated across quads
    float hpacc = 0.f;
    #pragma unroll
    for (int i = 0; i < 16; ++i) hpacc += __shfl(hv, i) * Wgat[i * 64 + lane];
    hp[(long)n * 64 + lane] = hpacc;
    hpb[(long)n * 64 + lane] = __float2half(hpacc);
    float ss = hpacc * a_src[lane];
    float sd = hpacc * a_dst[lane];
    #pragma unroll
    for (int off = 32; off; off >>= 1) {
        ss += __shfl_xor(ss, off);
        sd += __shfl_xor(sd, off);
    }
    if (lane == 0) { sc_s[n] = ss; sc_d[n] = sd; }
}

// ---------------- K3: GAT, wave per node, lane-parallel neighbor softmax ----------------
__global__ __launch_bounds__(256) void k_gat(const float* __restrict__ hp, const __half* __restrict__ hpb,
                     const float* __restrict__ sc_s, const float* __restrict__ sc_d,
                     const int* __restrict__ esrc, const int* __restrict__ cstart,
                     const float* __restrict__ bgat, float* __restrict__ gat) {
    int d = (blockIdx.x * blockDim.x + threadIdx.x) >> 6;
    int lane = threadIdx.x & 63;
    if (d >= NN) return;
    float sdv = sc_d[d];
    float e0 = sc_s[d] + sdv;                 // self loop
    e0 = (e0 >= 0.f) ? e0 : 0.2f * e0;
    float mx = e0, l = 1.f;
    float acc = hp[(long)d * 64 + lane];
    int a0 = cstart[d], a1 = cstart[d + 1];
    for (int base = a0; base < a1; base += 64) {
        int j = base + lane;
        bool valid = j < a1;
        int s = valid ? esrc[j] : 0;          // coalesced src ids
        float sc = valid ? sc_s[s] + sdv : -1e30f;
        sc = (sc >= 0.f) ? sc : 0.2f * sc;
        float cm = sc;
        #pragma unroll
        for (int off = 32; off; off >>= 1) cm = fmaxf(cm, __shfl_xor(cm, off));
        float nm = fmaxf(mx, cm);
        float pj = valid ? __expf(sc - nm) : 0.f;
        float ps = pj;
        #pragma unroll
        for (int off = 32; off; off >>= 1) ps += __shfl_xor(ps, off);
        float scale = __expf(mx - nm);
        l = l * scale + ps;
        acc *= scale;
        mx = nm;
        int cnt = a1 - base; if (cnt > 64) cnt = 64;
        int k2 = 0;
        for (; k2 + 4 <= cnt; k2 += 4) {
            int   s0 = __shfl(s, k2),     s1 = __shfl(s, k2 + 1);
            int   s2 = __shfl(s, k2 + 2), s3 = __shfl(s, k2 + 3);
            float p0 = __shfl(pj, k2),     p1 = __shfl(pj, k2 + 1);
            float p2 = __shfl(pj, k2 + 2), p3 = __shfl(pj, k2 + 3);
            float h0 = __half2float(hpb[(long)s0 * 64 + lane]);
            float h1 = __half2float(hpb[(long)s1 * 64 + lane]);
            float h2 = __half2float(hpb[(long)s2 * 64 + lane]);
            float h3 = __half2float(hpb[(long)s3 * 64 + lane]);
            acc += p0 * h0 + p1 * h1 + p2 * h2 + p3 * h3;
        }
        for (; k2 < cnt; ++k2) {
            int sk = __shfl(s, k2);
            float pk = __shfl(pj, k2);
            acc += pk * __half2float(hpb[(long)sk * 64 + lane]);
        }
    }
    float g = acc / l + bgat[lane];
    gat[(long)d * 64 + lane] = fmaxf(g, 0.f);
}

// ---------------- K4: mean pool per graph ----------------
static __device__ inline int lbound(const int* b, int key) {
    int lo = 0, hi = NN;
    while (lo < hi) { int mid = (lo + hi) >> 1; if (b[mid] < key) lo = mid + 1; else hi = mid; }
    return lo;
}
__global__ __launch_bounds__(256) void k_pool(const float* __restrict__ gat, const int* __restrict__ batch,
                      float* __restrict__ pooled) {
    int g = blockIdx.x;
    int r0 = lbound(batch, g);
    int r1 = lbound(batch, g + 1);
    int o = threadIdx.x & 63, gr = threadIdx.x >> 6;
    float part = 0.f;
    for (int r = r0 + gr; r < r1; r += 4) part += gat[(long)r * 64 + o];
    __shared__ float sd[256];
    sd[threadIdx.x] = part; __syncthreads();
    if (threadIdx.x < 64) {
        float tot = sd[o] + sd[64 + o] + sd[128 + o] + sd[192 + o];
        int cnt = r1 - r0;
        pooled[g * 64 + o] = tot / (float)(cnt > 0 ? cnt : 1);
    }
}

// ---------------- K5: MLP head, single block ----------------
__global__ __launch_bounds__(1024) void k_head(const float* __restrict__ pooled, const float* __restrict__ Wfc1,
                      const float* __restrict__ bfc1, const float* __restrict__ Wfc2,
                      const float* __restrict__ bfc2, float* __restrict__ out) {
    __shared__ float pl[NG * 64];
    __shared__ float zl[NG * 129];
    int t = threadIdx.x;
    for (int i = t; i < NG * 64; i += 1024) pl[i] = pooled[i];
    __syncthreads();
    int hcol = t & 127, gq = t >> 7;
    float acc[8];
    #pragma unroll
    for (int g8 = 0; g8 < 8; ++g8) acc[g8] = bfc1[hcol];
    for (int i = 0; i < 64; ++i) {
        float wf = Wfc1[i * 128 + hcol];
        #pragma unroll
        for (int g8 = 0; g8 < 8; ++g8) acc[g8] += pl[(gq * 8 + g8) * 64 + i] * wf;
    }
    #pragma unroll
    for (int g8 = 0; g8 < 8; ++g8) zl[(gq * 8 + g8) * 129 + hcol] = fmaxf(acc[g8], 0.f);
    __syncthreads();
    if (t < NG) {
        float a = bfc2[0];
        for (int hh = 0; hh < 128; ++hh) a += zl[t * 129 + hh] * Wfc2[hh];
        out[t] = a;
    }
}

extern "C" void kernel_launch(void* const* d_in, const int* in_sizes, int n_in,
                              void* d_out, int out_size, void* d_ws, size_t ws_size,
                              hipStream_t stream) {
    (void)in_sizes; (void)n_in; (void)out_size; (void)ws_size;
    const float* x     = (const float*)d_in[0];
    const int*   ei    = (const int*)d_in[1];
    const float* ea    = (const float*)d_in[2];
    const int*   batch = (const int*)d_in[3];
    const float* We    = (const float*)d_in[4];
    const float* be    = (const float*)d_in[5];
    const float* Wroot = (const float*)d_in[6];
    const float* bconv = (const float*)d_in[7];
    const float* Wgat  = (const float*)d_in[8];
    const float* a_src = (const float*)d_in[9];
    const float* a_dst = (const float*)d_in[10];
    const float* bgat  = (const float*)d_in[11];
    const float* Wfc1  = (const float*)d_in[12];
    const float* bfc1  = (const float*)d_in[13];
    const float* Wfc2  = (const float*)d_in[14];
    const float* bfc2  = (const float*)d_in[15];

    char* w = (char*)d_ws;
    size_t o0  = 0;                            // deg      NN int
    size_t o1  = o0  + (size_t)NN * 4;         // cursor   NN int (contiguous after deg)
    size_t o2  = o1  + (size_t)NN * 4;         // cstart   (NN+1) int
    size_t o3  = o2  + (size_t)(NN + 1) * 4;   // pos_e    NE int
    size_t o4  = o3  + (size_t)NE * 4;         // esrc     NE int
    size_t o5  = o4  + (size_t)NE * 4;         // msg      NE*16 f32 (CSR order)
    size_t o6  = o5  + (size_t)NE * 16 * 4;    // hp       NN*64 f32
    size_t o7  = o6  + (size_t)NN * 64 * 4;    // hpb      NN*64 f16
    size_t o8  = o7  + (size_t)NN * 64 * 2;    // sc_s     NN f32
    size_t o9  = o8  + (size_t)NN * 4;         // sc_d     NN f32
    size_t o10 = o9  + (size_t)NN * 4;         // gat      NN*64 f32
    size_t o11 = o10 + (size_t)NN * 64 * 4;    // pooled   NG*64 f32
    size_t o12 = o11 + (size_t)NG * 64 * 4;    // we2t     16*544 f16
    o12 = (o12 + 15) & ~(size_t)15;

    int* degcur   = (int*)(w + o0);
    int* deg      = (int*)(w + o0);
    int* cursor   = (int*)(w + o1);
    int* cstart   = (int*)(w + o2);
    int* pos_e    = (int*)(w + o3);
    int* esrc     = (int*)(w + o4);
    float* msg    = (float*)(w + o5);
    float* hp     = (float*)(w + o6);
    __half* hpb   = (__half*)(w + o7);
    float* sc_s   = (float*)(w + o8);
    float* sc_d   = (float*)(w + o9);
    float* gat    = (float*)(w + o10);
    float* pooled = (float*)(w + o11);
    __half* we2t  = (__half*)(w + o12);

    k_init<<<(2 * NN + 255) / 256, 256, 0, stream>>>(We, be, degcur, we2t);
    k_hist<<<(NE + 255) / 256, 256, 0, stream>>>(ei, deg);
    k_scan<<<1, 1024, 0, stream>>>(deg, cstart);
    k_fill<<<(NE + 255) / 256, 256, 0, stream>>>(ei, cstart, cursor, pos_e, esrc);
    k_msg<<<2500, 256, 0, stream>>>(x, ei, ea, we2t, pos_e, msg);
    k_node<<<(NN + 3) / 4, 256, 0, stream>>>(x, Wroot, bconv, msg, cstart, Wgat, a_src, a_dst,
                                             hp, hpb, sc_s, sc_d);
    k_gat<<<(NN + 3) / 4, 256, 0, stream>>>(hp, hpb, sc_s, sc_d, esrc, cstart, bgat, gat);
    k_pool<<<NG, 256, 0, stream>>>(gat, batch, pooled);
    k_head<<<1, 1024, 0, stream>>>(pooled, Wfc1, bfc1, Wfc2, bfc2, (float*)d_out);
}

// Round 7
// 248.912 us; speedup vs baseline: 1.2656x; 1.0260x over previous
//
#include <hip/hip_runtime.h>
#include <hip/hip_bf16.h>
#include <hip/hip_fp16.h>

#define NN 20000      // nodes
#define NE 320000     // edges
#define FE 32         // edge feature dim
#define DIN 16
#define DNN 16
#define DGAT 64
#define HID 128
#define NG 64         // graphs

using f16x8 = __attribute__((ext_vector_type(8))) _Float16;
using f32x4 = __attribute__((ext_vector_type(4))) float;
using nvf4  = __attribute__((ext_vector_type(4))) float;   // native vec4 for nontemporal builtins

union AFrag {
    f16x8 v;
    __half2 h2[4];
};

// ---------------- K0: fused histogram (rel position) + we2t build ----------------
// K permutation (owned by us, A and B agree): for k in [0,512):
//   ks=k>>5, r=k&31, q=r>>3, j=r&7 ; f = 16*(q>>1) + ks ; i = (q&1)*8 + j
// so a lane (quad q) needs ea[e, p*16 + ks], ks=0..15 -> CONTIGUOUS 16 floats.
// k in [512,528): bias row i=k-512 ; k in [528,544): zero.
__global__ void k_histinit(const int* __restrict__ ei, int* __restrict__ deg,
                           int* __restrict__ rel_e,
                           const float* __restrict__ We, const float* __restrict__ be,
                           __half* __restrict__ we2t) {
    int e = blockIdx.x * blockDim.x + threadIdx.x;
    if (e < NE) rel_e[e] = atomicAdd(&deg[ei[NE + e]], 1);
    if (e < 16 * 544) {
        int k = e % 544, m = e / 544;
        float v;
        if (k < 512) {
            int ks = k >> 5, r = k & 31, q = r >> 3, j = r & 7;
            int f = 16 * (q >> 1) + ks;
            int i = (q & 1) * 8 + j;
            v = We[f * 256 + i * 16 + m];
        } else if (k < 528) {
            int i = k - 512;
            v = be[i * 16 + m];
        } else v = 0.f;
        we2t[e] = __float2half(v);
    }
}

// ---------------- K0b: single-block exclusive scan of deg -> cstart ----------------
#define SCAN_K 20
__global__ __launch_bounds__(1024) void k_scan(const int* __restrict__ deg, int* __restrict__ cstart) {
    __shared__ int sd[1024];
    int t = threadIdx.x;
    int base = t * SCAN_K;
    int vals[SCAN_K];
    int s = 0;
    #pragma unroll
    for (int k = 0; k < SCAN_K; ++k) {
        int i = base + k;
        int v = (i < NN) ? deg[i] : 0;
        vals[k] = s; s += v;
    }
    sd[t] = s; __syncthreads();
    for (int off = 1; off < 1024; off <<= 1) {
        int add = (t >= off) ? sd[t - off] : 0;
        __syncthreads();
        sd[t] += add;
        __syncthreads();
    }
    int excl = (t == 0) ? 0 : sd[t - 1];
    #pragma unroll
    for (int k = 0; k < SCAN_K; ++k) {
        int i = base + k;
        if (i <= NN) cstart[i] = excl + vals[k];
    }
}

// ---------------- K1: NNConv messages, fp16 MFMA, CSR-ordered output, fused fill ----------------
__global__ __launch_bounds__(256, 1) void k_msg(
    const float* __restrict__ x, const int* __restrict__ ei,
    const float* __restrict__ ea, const __half* __restrict__ we2t,
    const int* __restrict__ rel_e, const int* __restrict__ cstart,
    float* __restrict__ msg, int* __restrict__ esrc)
{
    const int lane = threadIdx.x & 63;
    const int wid  = threadIdx.x >> 6;
    const int m    = lane & 15;      // A-row (edge) for loads; C col (output o) for stores
    const int quad = lane >> 4;
    const int p    = quad >> 1;      // ea half selector
    const int xh   = (quad & 1) * 8; // x half

    // B fragments: 17 aligned 16B loads from precomputed (K-permuted) f16 table.
    const __half* wt = we2t + m * 544 + quad * 8;
    f16x8 bfr[17];
    #pragma unroll
    for (int ks = 0; ks < 17; ++ks)
        bfr[ks] = *(const f16x8*)(wt + ks * 32);

    const int* srcp = ei;
    const int* dstp = ei + NE;

    const int t0  = (blockIdx.x * 4 + wid) * 2;
    const int e0A = t0 * 16, e0B = e0A + 16;
    const int rA  = e0A + quad * 4 + (m & 3);   // the C row this lane resolves CSR pos for
    const int rB  = e0B + quad * 4 + (m & 3);

    // ---- hoist ALL loads for both tiles ----
    const int sA = srcp[e0A + m];
    const int sB = srcp[e0B + m];
    const int dA = dstp[rA],  dB = dstp[rB];
    const int relA = rel_e[rA], relB = rel_e[rB];
    const int srcA = srcp[rA], srcB = srcp[rB];

    nvf4 evA[4], evB[4];
    {
        const nvf4* eaA = (const nvf4*)(ea + (long)(e0A + m) * 32 + p * 16);
        const nvf4* eaB = (const nvf4*)(ea + (long)(e0B + m) * 32 + p * 16);
        #pragma unroll
        for (int q = 0; q < 4; ++q) {
            evA[q] = __builtin_nontemporal_load(eaA + q);
            evB[q] = __builtin_nontemporal_load(eaB + q);
        }
    }
    float xfA[8], xfB[8];
    {
        const float4* xrA = (const float4*)(x + sA * 16 + xh);
        const float4* xrB = (const float4*)(x + sB * 16 + xh);
        float4 a0 = xrA[0], a1 = xrA[1], b0 = xrB[0], b1 = xrB[1];
        xfA[0]=a0.x; xfA[1]=a0.y; xfA[2]=a0.z; xfA[3]=a0.w;
        xfA[4]=a1.x; xfA[5]=a1.y; xfA[6]=a1.z; xfA[7]=a1.w;
        xfB[0]=b0.x; xfB[1]=b0.y; xfB[2]=b0.z; xfB[3]=b0.w;
        xfB[4]=b1.x; xfB[5]=b1.y; xfB[6]=b1.z; xfB[7]=b1.w;
    }
    const int cA = cstart[dA] + relA;
    const int cB = cstart[dB] + relB;
    if (m < 4) { esrc[cA] = srcA; esrc[cB] = srcB; }   // one writer per C row

    // ---- tile A ----
    {
        __half2 xp[4];
        #pragma unroll
        for (int j = 0; j < 4; ++j)
            xp[j] = __float22half2_rn(make_float2(xfA[2*j], xfA[2*j+1]));
        f32x4 acc = {0.f, 0.f, 0.f, 0.f};
        #pragma unroll
        for (int ks = 0; ks < 16; ++ks) {
            float ev = ((const float*)evA)[ks];
            __half2 eh = __float2half2_rn(ev);
            AFrag a;
            #pragma unroll
            for (int j = 0; j < 4; ++j) a.h2[j] = __hmul2(eh, xp[j]);
            acc = __builtin_amdgcn_mfma_f32_16x16x32_f16(a.v, bfr[ks], acc, 0, 0, 0);
        }
        {
            AFrag a;
            #pragma unroll
            for (int j = 0; j < 4; ++j) a.h2[j] = xp[j];
            acc = __builtin_amdgcn_mfma_f32_16x16x32_f16(a.v, bfr[16], acc, 0, 0, 0);
        }
        #pragma unroll
        for (int r = 0; r < 4; ++r) {
            int c = __shfl(cA, (quad << 4) | r);
            msg[(long)c * 16 + m] = acc[r];
        }
    }
    // ---- tile B ----
    {
        __half2 xp[4];
        #pragma unroll
        for (int j = 0; j < 4; ++j)
            xp[j] = __float22half2_rn(make_float2(xfB[2*j], xfB[2*j+1]));
        f32x4 acc = {0.f, 0.f, 0.f, 0.f};
        #pragma unroll
        for (int ks = 0; ks < 16; ++ks) {
            float ev = ((const float*)evB)[ks];
            __half2 eh = __float2half2_rn(ev);
            AFrag a;
            #pragma unroll
            for (int j = 0; j < 4; ++j) a.h2[j] = __hmul2(eh, xp[j]);
            acc = __builtin_amdgcn_mfma_f32_16x16x32_f16(a.v, bfr[ks], acc, 0, 0, 0);
        }
        {
            AFrag a;
            #pragma unroll
            for (int j = 0; j < 4; ++j) a.h2[j] = xp[j];
            acc = __builtin_amdgcn_mfma_f32_16x16x32_f16(a.v, bfr[16], acc, 0, 0, 0);
        }
        #pragma unroll
        for (int r = 0; r < 4; ++r) {
            int c = __shfl(cB, (quad << 4) | r);
            msg[(long)c * 16 + m] = acc[r];
        }
    }
}

// ---------------- K2: fused NNConv-finish + GAT projection; wave per node ----------------
__global__ __launch_bounds__(256) void k_node(
    const float* __restrict__ x, const float* __restrict__ Wroot,
    const float* __restrict__ bconv, const float* __restrict__ msg,
    const int* __restrict__ cstart, const float* __restrict__ Wgat,
    const float* __restrict__ a_src, const float* __restrict__ a_dst,
    float* __restrict__ hp, __half* __restrict__ hpb,
    float* __restrict__ sc_s, float* __restrict__ sc_d)
{
    int n = (blockIdx.x * blockDim.x + threadIdx.x) >> 6;
    int lane = threadIdx.x & 63;
    if (n >= NN) return;
    int o = lane & 15, g4 = lane >> 4;
    int a0 = cstart[n], a1 = cstart[n + 1];
    float part = 0.f;
    for (int j = a0 + g4; j < a1; j += 4) part += msg[(long)j * 16 + o];  // contiguous rows
    part += __shfl_xor(part, 16);
    part += __shfl_xor(part, 32);
    float xv = x[n * 16 + o];
    float acc = bconv[o] + part;
    #pragma unroll
    for (int i = 0; i < 16; ++i) acc += __shfl(xv, i) * Wroot[i * 16 + o];
    float hv = fmaxf(acc, 0.f);                  // replicated across quads
    float hpacc = 0.f;
    #pragma unroll
    for (int i = 0; i < 16; ++i) hpacc += __shfl(hv, i) * Wgat[i * 64 + lane];
    hp[(long)n * 64 + lane] = hpacc;
    hpb[(long)n * 64 + lane] = __float2half(hpacc);
    float ss = hpacc * a_src[lane];
    float sd = hpacc * a_dst[lane];
    #pragma unroll
    for (int off = 32; off; off >>= 1) {
        ss += __shfl_xor(ss, off);
        sd += __shfl_xor(sd, off);
    }
    if (lane == 0) { sc_s[n] = ss; sc_d[n] = sd; }
}

// ---------------- K3: GAT, wave per node, lane-parallel neighbor softmax ----------------
__global__ __launch_bounds__(256) void k_gat(const float* __restrict__ hp, const __half* __restrict__ hpb,
                     const float* __restrict__ sc_s, const float* __restrict__ sc_d,
                     const int* __restrict__ esrc, const int* __restrict__ cstart,
                     const float* __restrict__ bgat, float* __restrict__ gat) {
    int d = (blockIdx.x * blockDim.x + threadIdx.x) >> 6;
    int lane = threadIdx.x & 63;
    if (d >= NN) return;
    float sdv = sc_d[d];
    float e0 = sc_s[d] + sdv;                 // self loop
    e0 = (e0 >= 0.f) ? e0 : 0.2f * e0;
    float mx = e0, l = 1.f;
    float acc = hp[(long)d * 64 + lane];
    int a0 = cstart[d], a1 = cstart[d + 1];
    for (int base = a0; base < a1; base += 64) {
        int j = base + lane;
        bool valid = j < a1;
        int s = valid ? esrc[j] : 0;          // coalesced src ids
        float sc = valid ? sc_s[s] + sdv : -1e30f;
        sc = (sc >= 0.f) ? sc : 0.2f * sc;
        float cm = sc;
        #pragma unroll
        for (int off = 32; off; off >>= 1) cm = fmaxf(cm, __shfl_xor(cm, off));
        float nm = fmaxf(mx, cm);
        float pj = valid ? __expf(sc - nm) : 0.f;
        float ps = pj;
        #pragma unroll
        for (int off = 32; off; off >>= 1) ps += __shfl_xor(ps, off);
        float scale = __expf(mx - nm);
        l = l * scale + ps;
        acc *= scale;
        mx = nm;
        int cnt = a1 - base; if (cnt > 64) cnt = 64;
        int k2 = 0;
        for (; k2 + 4 <= cnt; k2 += 4) {
            int   s0 = __shfl(s, k2),     s1 = __shfl(s, k2 + 1);
            int   s2 = __shfl(s, k2 + 2), s3 = __shfl(s, k2 + 3);
            float p0 = __shfl(pj, k2),     p1 = __shfl(pj, k2 + 1);
            float p2 = __shfl(pj, k2 + 2), p3 = __shfl(pj, k2 + 3);
            float h0 = __half2float(hpb[(long)s0 * 64 + lane]);
            float h1 = __half2float(hpb[(long)s1 * 64 + lane]);
            float h2 = __half2float(hpb[(long)s2 * 64 + lane]);
            float h3 = __half2float(hpb[(long)s3 * 64 + lane]);
            acc += p0 * h0 + p1 * h1 + p2 * h2 + p3 * h3;
        }
        for (; k2 < cnt; ++k2) {
            int sk = __shfl(s, k2);
            float pk = __shfl(pj, k2);
            acc += pk * __half2float(hpb[(long)sk * 64 + lane]);
        }
    }
    float g = acc / l + bgat[lane];
    gat[(long)d * 64 + lane] = fmaxf(g, 0.f);
}

// ---------------- K4: mean pool per graph ----------------
static __device__ inline int lbound(const int* b, int key) {
    int lo = 0, hi = NN;
    while (lo < hi) { int mid = (lo + hi) >> 1; if (b[mid] < key) lo = mid + 1; else hi = mid; }
    return lo;
}
__global__ __launch_bounds__(256) void k_pool(const float* __restrict__ gat, const int* __restrict__ batch,
                      float* __restrict__ pooled) {
    int g = blockIdx.x;
    int r0 = lbound(batch, g);
    int r1 = lbound(batch, g + 1);
    int o = threadIdx.x & 63, gr = threadIdx.x >> 6;
    float part = 0.f;
    for (int r = r0 + gr; r < r1; r += 4) part += gat[(long)r * 64 + o];
    __shared__ float sd[256];
    sd[threadIdx.x] = part; __syncthreads();
    if (threadIdx.x < 64) {
        float tot = sd[o] + sd[64 + o] + sd[128 + o] + sd[192 + o];
        int cnt = r1 - r0;
        pooled[g * 64 + o] = tot / (float)(cnt > 0 ? cnt : 1);
    }
}

// ---------------- K5: MLP head, single block ----------------
__global__ __launch_bounds__(1024) void k_head(const float* __restrict__ pooled, const float* __restrict__ Wfc1,
                      const float* __restrict__ bfc1, const float* __restrict__ Wfc2,
                      const float* __restrict__ bfc2, float* __restrict__ out) {
    __shared__ float pl[NG * 64];
    __shared__ float zl[NG * 129];
    int t = threadIdx.x;
    for (int i = t; i < NG * 64; i += 1024) pl[i] = pooled[i];
    __syncthreads();
    int hcol = t & 127, gq = t >> 7;
    float acc[8];
    #pragma unroll
    for (int g8 = 0; g8 < 8; ++g8) acc[g8] = bfc1[hcol];
    for (int i = 0; i < 64; ++i) {
        float wf = Wfc1[i * 128 + hcol];
        #pragma unroll
        for (int g8 = 0; g8 < 8; ++g8) acc[g8] += pl[(gq * 8 + g8) * 64 + i] * wf;
    }
    #pragma unroll
    for (int g8 = 0; g8 < 8; ++g8) zl[(gq * 8 + g8) * 129 + hcol] = fmaxf(acc[g8], 0.f);
    __syncthreads();
    if (t < NG) {
        float a = bfc2[0];
        for (int hh = 0; hh < 128; ++hh) a += zl[t * 129 + hh] * Wfc2[hh];
        out[t] = a;
    }
}

extern "C" void kernel_launch(void* const* d_in, const int* in_sizes, int n_in,
                              void* d_out, int out_size, void* d_ws, size_t ws_size,
                              hipStream_t stream) {
    (void)in_sizes; (void)n_in; (void)out_size; (void)ws_size;
    const float* x     = (const float*)d_in[0];
    const int*   ei    = (const int*)d_in[1];
    const float* ea    = (const float*)d_in[2];
    const int*   batch = (const int*)d_in[3];
    const float* We    = (const float*)d_in[4];
    const float* be    = (const float*)d_in[5];
    const float* Wroot = (const float*)d_in[6];
    const float* bconv = (const float*)d_in[7];
    const float* Wgat  = (const float*)d_in[8];
    const float* a_src = (const float*)d_in[9];
    const float* a_dst = (const float*)d_in[10];
    const float* bgat  = (const float*)d_in[11];
    const float* Wfc1  = (const float*)d_in[12];
    const float* bfc1  = (const float*)d_in[13];
    const float* Wfc2  = (const float*)d_in[14];
    const float* bfc2  = (const float*)d_in[15];

    char* w = (char*)d_ws;
    size_t o0  = 0;                            // deg      NN int
    size_t o1  = o0  + (size_t)NN * 4;         // cstart   (NN+1) int
    size_t o2  = o1  + (size_t)(NN + 1) * 4;   // rel_e    NE int
    size_t o3  = o2  + (size_t)NE * 4;         // esrc     NE int
    size_t o4  = o3  + (size_t)NE * 4;         // msg      NE*16 f32 (CSR order)
    size_t o5  = o4  + (size_t)NE * 16 * 4;    // hp       NN*64 f32
    size_t o6  = o5  + (size_t)NN * 64 * 4;    // hpb      NN*64 f16
    size_t o7  = o6  + (size_t)NN * 64 * 2;    // sc_s     NN f32
    size_t o8  = o7  + (size_t)NN * 4;         // sc_d     NN f32
    size_t o9  = o8  + (size_t)NN * 4;         // gat      NN*64 f32
    size_t o10 = o9  + (size_t)NN * 64 * 4;    // pooled   NG*64 f32
    size_t o11 = o10 + (size_t)NG * 64 * 4;    // we2t     16*544 f16
    o11 = (o11 + 15) & ~(size_t)15;

    int* deg      = (int*)(w + o0);
    int* cstart   = (int*)(w + o1);
    int* rel_e    = (int*)(w + o2);
    int* esrc     = (int*)(w + o3);
    float* msg    = (float*)(w + o4);
    float* hp     = (float*)(w + o5);
    __half* hpb   = (__half*)(w + o6);
    float* sc_s   = (float*)(w + o7);
    float* sc_d   = (float*)(w + o8);
    float* gat    = (float*)(w + o9);
    float* pooled = (float*)(w + o10);
    __half* we2t  = (__half*)(w + o11);

    (void)hipMemsetAsync(deg, 0, (size_t)NN * 4, stream);
    k_histinit<<<(NE + 255) / 256, 256, 0, stream>>>(ei, deg, rel_e, We, be, we2t);
    k_scan<<<1, 1024, 0, stream>>>(deg, cstart);
    k_msg<<<2500, 256, 0, stream>>>(x, ei, ea, we2t, rel_e, cstart, msg, esrc);
    k_node<<<(NN + 3) / 4, 256, 0, stream>>>(x, Wroot, bconv, msg, cstart, Wgat, a_src, a_dst,
                                             hp, hpb, sc_s, sc_d);
    k_gat<<<(NN + 3) / 4, 256, 0, stream>>>(hp, hpb, sc_s, sc_d, esrc, cstart, bgat, gat);
    k_pool<<<NG, 256, 0, stream>>>(gat, batch, pooled);
    k_head<<<1, 1024, 0, stream>>>(pooled, Wfc1, bfc1, Wfc2, bfc2, (float*)d_out);
}

// Round 8
// 236.268 us; speedup vs baseline: 1.3333x; 1.0535x over previous
//
#include <hip/hip_runtime.h>
#include <hip/hip_bf16.h>
#include <hip/hip_fp16.h>

#define NN 20000      // nodes
#define NE 320000     // edges
#define FE 32         // edge feature dim
#define DIN 16
#define DNN 16
#define DGAT 64
#define HID 128
#define NG 64         // graphs

using f16x8 = __attribute__((ext_vector_type(8))) _Float16;
using f32x4 = __attribute__((ext_vector_type(4))) float;

union AFrag {
    f16x8 v;
    __half2 h2[4];
};

// ---------------- K0: fused histogram (rel position) + we2t build ----------------
// K permutation (owned by us, A and B agree): for k in [0,512):
//   ks=k>>5, r=k&31, q=r>>3, j=r&7 ; f = 16*(q>>1) + ks ; i = (q&1)*8 + j
// so a lane (quad q) needs ea[e, p*16 + ks], ks=0..15 -> CONTIGUOUS 16 floats.
// k in [512,528): bias row i=k-512 ; k in [528,544): zero.
__global__ void k_histinit(const int* __restrict__ ei, int* __restrict__ deg,
                           int* __restrict__ rel_e,
                           const float* __restrict__ We, const float* __restrict__ be,
                           __half* __restrict__ we2t) {
    int e = blockIdx.x * blockDim.x + threadIdx.x;
    if (e < NE) rel_e[e] = atomicAdd(&deg[ei[NE + e]], 1);
    if (e < 16 * 544) {
        int k = e % 544, m = e / 544;
        float v;
        if (k < 512) {
            int ks = k >> 5, r = k & 31, q = r >> 3, j = r & 7;
            int f = 16 * (q >> 1) + ks;
            int i = (q & 1) * 8 + j;
            v = We[f * 256 + i * 16 + m];
        } else if (k < 528) {
            int i = k - 512;
            v = be[i * 16 + m];
        } else v = 0.f;
        we2t[e] = __float2half(v);
    }
}

// ---------------- K0b: single-block exclusive scan of deg -> cstart (int4 loads) ----------------
#define SCAN_K 20
__global__ __launch_bounds__(1024) void k_scan(const int* __restrict__ deg, int* __restrict__ cstart) {
    __shared__ int sd[1024];
    int t = threadIdx.x;
    int base = t * SCAN_K;
    int vals[SCAN_K];
    int s = 0;
    if (base + SCAN_K <= NN) {          // t < 1000 exactly (NN = 20000)
        const int4* dv = (const int4*)(deg + base);
        int4 b[5];
        #pragma unroll
        for (int q = 0; q < 5; ++q) b[q] = dv[q];
        const int* bb = (const int*)b;
        #pragma unroll
        for (int k = 0; k < SCAN_K; ++k) { vals[k] = s; s += bb[k]; }
    } else {
        #pragma unroll
        for (int k = 0; k < SCAN_K; ++k) { vals[k] = s; }
    }
    sd[t] = s; __syncthreads();
    for (int off = 1; off < 1024; off <<= 1) {
        int add = (t >= off) ? sd[t - off] : 0;
        __syncthreads();
        sd[t] += add;
        __syncthreads();
    }
    int excl = (t == 0) ? 0 : sd[t - 1];
    #pragma unroll
    for (int k = 0; k < SCAN_K; ++k) {
        int i = base + k;
        if (i <= NN) cstart[i] = excl + vals[k];
    }
}

// ---------------- K1: NNConv messages; 1 tile per wave (max TLP), CSR-ordered output ----------------
__global__ __launch_bounds__(256) void k_msg(
    const float* __restrict__ x, const int* __restrict__ ei,
    const float* __restrict__ ea, const __half* __restrict__ we2t,
    const int* __restrict__ rel_e, const int* __restrict__ cstart,
    float* __restrict__ msg, int* __restrict__ esrc)
{
    const int lane = threadIdx.x & 63;
    const int wid  = threadIdx.x >> 6;
    const int m    = lane & 15;      // A-row (edge) for loads; C col (output o) for stores
    const int quad = lane >> 4;
    const int p    = quad >> 1;      // ea half selector
    const int xh   = (quad & 1) * 8; // x half

    const int tile = blockIdx.x * 4 + wid;   // 5000 blocks x 4 waves = 20000 tiles
    const int e0   = tile * 16;
    const int r    = e0 + quad * 4 + (m & 3);   // C row this lane resolves CSR pos for

    // ---- issue the whole load batch for this tile ----
    const int s   = ei[e0 + m];
    const int d   = ei[NE + r];
    const int rel = rel_e[r];
    const int src = ei[r];

    float4 ev[4];
    {
        const float4* ear = (const float4*)(ea + (long)(e0 + m) * 32 + p * 16);
        #pragma unroll
        for (int q = 0; q < 4; ++q) ev[q] = ear[q];
    }
    float xf[8];
    {
        const float4* xr = (const float4*)(x + s * 16 + xh);
        float4 a0 = xr[0], a1 = xr[1];
        xf[0]=a0.x; xf[1]=a0.y; xf[2]=a0.z; xf[3]=a0.w;
        xf[4]=a1.x; xf[5]=a1.y; xf[6]=a1.z; xf[7]=a1.w;
    }
    const int c = cstart[d] + rel;
    if (m < 4) esrc[c] = src;                 // one writer per C row

    // B fragments: 17 aligned 16B loads from precomputed (K-permuted) f16 table.
    const __half* wt = we2t + m * 544 + quad * 8;
    f16x8 bfr[17];
    #pragma unroll
    for (int ks = 0; ks < 17; ++ks)
        bfr[ks] = *(const f16x8*)(wt + ks * 32);

    __half2 xp[4];
    #pragma unroll
    for (int j = 0; j < 4; ++j)
        xp[j] = __float22half2_rn(make_float2(xf[2*j], xf[2*j+1]));

    f32x4 acc = {0.f, 0.f, 0.f, 0.f};
    #pragma unroll
    for (int ks = 0; ks < 16; ++ks) {
        float evv = ((const float*)ev)[ks];
        __half2 eh = __float2half2_rn(evv);
        AFrag a;
        #pragma unroll
        for (int j = 0; j < 4; ++j) a.h2[j] = __hmul2(eh, xp[j]);
        acc = __builtin_amdgcn_mfma_f32_16x16x32_f16(a.v, bfr[ks], acc, 0, 0, 0);
    }
    {
        AFrag a;
        #pragma unroll
        for (int j = 0; j < 4; ++j) a.h2[j] = xp[j];
        acc = __builtin_amdgcn_mfma_f32_16x16x32_f16(a.v, bfr[16], acc, 0, 0, 0);
    }
    #pragma unroll
    for (int rr = 0; rr < 4; ++rr) {
        int cc = __shfl(c, (quad << 4) | rr);
        msg[(long)cc * 16 + m] = acc[rr];
    }
}

// ---------------- K2: fused NNConv-finish + GAT projection; wave per node ----------------
__global__ __launch_bounds__(256) void k_node(
    const float* __restrict__ x, const float* __restrict__ Wroot,
    const float* __restrict__ bconv, const float* __restrict__ msg,
    const int* __restrict__ cstart, const float* __restrict__ Wgat,
    const float* __restrict__ a_src, const float* __restrict__ a_dst,
    __half* __restrict__ hpb, float* __restrict__ sc_s, float* __restrict__ sc_d)
{
    int n = (blockIdx.x * blockDim.x + threadIdx.x) >> 6;
    int lane = threadIdx.x & 63;
    if (n >= NN) return;
    int o = lane & 15, g4 = lane >> 4;
    int a0 = cstart[n], a1 = cstart[n + 1];
    float part = 0.f;
    for (int j = a0 + g4; j < a1; j += 4) part += msg[(long)j * 16 + o];  // contiguous rows
    part += __shfl_xor(part, 16);
    part += __shfl_xor(part, 32);
    float xv = x[n * 16 + o];
    float acc = bconv[o] + part;
    #pragma unroll
    for (int i = 0; i < 16; ++i) acc += __shfl(xv, i) * Wroot[i * 16 + o];
    float hv = fmaxf(acc, 0.f);                  // replicated across quads
    float hpacc = 0.f;
    #pragma unroll
    for (int i = 0; i < 16; ++i) hpacc += __shfl(hv, i) * Wgat[i * 64 + lane];
    hpb[(long)n * 64 + lane] = __float2half(hpacc);
    float ss = hpacc * a_src[lane];
    float sd = hpacc * a_dst[lane];
    #pragma unroll
    for (int off = 32; off; off >>= 1) {
        ss += __shfl_xor(ss, off);
        sd += __shfl_xor(sd, off);
    }
    if (lane == 0) { sc_s[n] = ss; sc_d[n] = sd; }
}

// ---------------- K3: GAT, wave per node, lane-parallel neighbor softmax ----------------
__global__ __launch_bounds__(256) void k_gat(const __half* __restrict__ hpb,
                     const float* __restrict__ sc_s, const float* __restrict__ sc_d,
                     const int* __restrict__ esrc, const int* __restrict__ cstart,
                     const float* __restrict__ bgat, float* __restrict__ gat) {
    int d = (blockIdx.x * blockDim.x + threadIdx.x) >> 6;
    int lane = threadIdx.x & 63;
    if (d >= NN) return;
    float sdv = sc_d[d];
    float e0 = sc_s[d] + sdv;                 // self loop
    e0 = (e0 >= 0.f) ? e0 : 0.2f * e0;
    float mx = e0, l = 1.f;
    float acc = __half2float(hpb[(long)d * 64 + lane]);
    int a0 = cstart[d], a1 = cstart[d + 1];
    for (int base = a0; base < a1; base += 64) {
        int j = base + lane;
        bool valid = j < a1;
        int s = valid ? esrc[j] : 0;          // coalesced src ids
        float sc = valid ? sc_s[s] + sdv : -1e30f;
        sc = (sc >= 0.f) ? sc : 0.2f * sc;
        float cm = sc;
        #pragma unroll
        for (int off = 32; off; off >>= 1) cm = fmaxf(cm, __shfl_xor(cm, off));
        float nm = fmaxf(mx, cm);
        float pj = valid ? __expf(sc - nm) : 0.f;
        float ps = pj;
        #pragma unroll
        for (int off = 32; off; off >>= 1) ps += __shfl_xor(ps, off);
        float scale = __expf(mx - nm);
        l = l * scale + ps;
        acc *= scale;
        mx = nm;
        int cnt = a1 - base; if (cnt > 64) cnt = 64;
        int k2 = 0;
        for (; k2 + 4 <= cnt; k2 += 4) {
            int   s0 = __shfl(s, k2),     s1 = __shfl(s, k2 + 1);
            int   s2 = __shfl(s, k2 + 2), s3 = __shfl(s, k2 + 3);
            float p0 = __shfl(pj, k2),     p1 = __shfl(pj, k2 + 1);
            float p2 = __shfl(pj, k2 + 2), p3 = __shfl(pj, k2 + 3);
            float h0 = __half2float(hpb[(long)s0 * 64 + lane]);
            float h1 = __half2float(hpb[(long)s1 * 64 + lane]);
            float h2 = __half2float(hpb[(long)s2 * 64 + lane]);
            float h3 = __half2float(hpb[(long)s3 * 64 + lane]);
            acc += p0 * h0 + p1 * h1 + p2 * h2 + p3 * h3;
        }
        for (; k2 < cnt; ++k2) {
            int sk = __shfl(s, k2);
            float pk = __shfl(pj, k2);
            acc += pk * __half2float(hpb[(long)sk * 64 + lane]);
        }
    }
    float g = acc / l + bgat[lane];
    gat[(long)d * 64 + lane] = fmaxf(g, 0.f);
}

// ---------------- K4: fused mean-pool + MLP head; one block per graph ----------------
static __device__ inline int lbound(const int* b, int key) {
    int lo = 0, hi = NN;
    while (lo < hi) { int mid = (lo + hi) >> 1; if (b[mid] < key) lo = mid + 1; else hi = mid; }
    return lo;
}
__global__ __launch_bounds__(256) void k_poolhead(
    const float* __restrict__ gat, const int* __restrict__ batch,
    const float* __restrict__ Wfc1, const float* __restrict__ bfc1,
    const float* __restrict__ Wfc2, const float* __restrict__ bfc2,
    float* __restrict__ out)
{
    int g = blockIdx.x;
    int t = threadIdx.x;
    int r0 = lbound(batch, g);
    int r1 = lbound(batch, g + 1);
    int o = t & 63, gr = t >> 6;
    float part = 0.f;
    for (int r = r0 + gr; r < r1; r += 4) part += gat[(long)r * 64 + o];
    __shared__ float sd[256];
    __shared__ float pooled[64];
    __shared__ float zl[128];
    sd[t] = part; __syncthreads();
    if (t < 64) {
        float tot = sd[t] + sd[64 + t] + sd[128 + t] + sd[192 + t];
        int cnt = r1 - r0;
        pooled[t] = tot / (float)(cnt > 0 ? cnt : 1);
    }
    __syncthreads();
    if (t < 128) {
        float a = bfc1[t];
        #pragma unroll 8
        for (int i = 0; i < 64; ++i) a += pooled[i] * Wfc1[i * 128 + t];
        zl[t] = fmaxf(a, 0.f);
    }
    __syncthreads();
    if (t < 64) {
        float v = zl[t] * Wfc2[t] + zl[t + 64] * Wfc2[t + 64];
        #pragma unroll
        for (int off = 32; off; off >>= 1) v += __shfl_xor(v, off);
        if (t == 0) out[g] = v + bfc2[0];
    }
}

extern "C" void kernel_launch(void* const* d_in, const int* in_sizes, int n_in,
                              void* d_out, int out_size, void* d_ws, size_t ws_size,
                              hipStream_t stream) {
    (void)in_sizes; (void)n_in; (void)out_size; (void)ws_size;
    const float* x     = (const float*)d_in[0];
    const int*   ei    = (const int*)d_in[1];
    const float* ea    = (const float*)d_in[2];
    const int*   batch = (const int*)d_in[3];
    const float* We    = (const float*)d_in[4];
    const float* be    = (const float*)d_in[5];
    const float* Wroot = (const float*)d_in[6];
    const float* bconv = (const float*)d_in[7];
    const float* Wgat  = (const float*)d_in[8];
    const float* a_src = (const float*)d_in[9];
    const float* a_dst = (const float*)d_in[10];
    const float* bgat  = (const float*)d_in[11];
    const float* Wfc1  = (const float*)d_in[12];
    const float* bfc1  = (const float*)d_in[13];
    const float* Wfc2  = (const float*)d_in[14];
    const float* bfc2  = (const float*)d_in[15];

    char* w = (char*)d_ws;
    size_t o0  = 0;                            // deg      NN int
    size_t o1  = o0  + (size_t)NN * 4;         // cstart   (NN+1) int
    size_t o2  = o1  + (size_t)(NN + 1) * 4;   // rel_e    NE int
    size_t o3  = o2  + (size_t)NE * 4;         // esrc     NE int
    size_t o4  = o3  + (size_t)NE * 4;         // msg      NE*16 f32 (CSR order)
    size_t o5  = o4  + (size_t)NE * 16 * 4;    // hpb      NN*64 f16
    size_t o6  = o5  + (size_t)NN * 64 * 2;    // sc_s     NN f32
    size_t o7  = o6  + (size_t)NN * 4;         // sc_d     NN f32
    size_t o8  = o7  + (size_t)NN * 4;         // gat      NN*64 f32
    size_t o9  = o8  + (size_t)NN * 64 * 4;    // we2t     16*544 f16
    o9 = (o9 + 15) & ~(size_t)15;

    int* deg      = (int*)(w + o0);
    int* cstart   = (int*)(w + o1);
    int* rel_e    = (int*)(w + o2);
    int* esrc     = (int*)(w + o3);
    float* msg    = (float*)(w + o4);
    __half* hpb   = (__half*)(w + o5);
    float* sc_s   = (float*)(w + o6);
    float* sc_d   = (float*)(w + o7);
    float* gat    = (float*)(w + o8);
    __half* we2t  = (__half*)(w + o9);

    (void)hipMemsetAsync(deg, 0, (size_t)NN * 4, stream);
    k_histinit<<<(NE + 255) / 256, 256, 0, stream>>>(ei, deg, rel_e, We, be, we2t);
    k_scan<<<1, 1024, 0, stream>>>(deg, cstart);
    k_msg<<<5000, 256, 0, stream>>>(x, ei, ea, we2t, rel_e, cstart, msg, esrc);
    k_node<<<(NN + 3) / 4, 256, 0, stream>>>(x, Wroot, bconv, msg, cstart, Wgat, a_src, a_dst,
                                             hpb, sc_s, sc_d);
    k_gat<<<(NN + 3) / 4, 256, 0, stream>>>(hpb, sc_s, sc_d, esrc, cstart, bgat, gat);
    k_poolhead<<<NG, 256, 0, stream>>>(gat, batch, Wfc1, bfc1, Wfc2, bfc2, (float*)d_out);
}

// Round 9
// 230.942 us; speedup vs baseline: 1.3641x; 1.0231x over previous
//
#include <hip/hip_runtime.h>
#include <hip/hip_bf16.h>
#include <hip/hip_fp16.h>

#define NN 20000      // nodes
#define NE 320000     // edges
#define FE 32         // edge feature dim
#define DIN 16
#define DNN 16
#define DGAT 64
#define HID 128
#define NG 64         // graphs

using f16x8 = __attribute__((ext_vector_type(8))) _Float16;
using f32x4 = __attribute__((ext_vector_type(4))) float;

union AFrag {
    f16x8 v;
    __half2 h2[4];
};

// ---------------- K0: fused histogram (rel position) + we2t build ----------------
// K permutation (owned by us, A and B agree): for k in [0,512):
//   ks=k>>5, r=k&31, q=r>>3, j=r&7 ; f = 16*(q>>1) + ks ; i = (q&1)*8 + j
// so a lane (quad q) needs ea[e, p*16 + ks], ks=0..15.
// k in [512,528): bias row i=k-512 ; k in [528,544): zero.
__global__ void k_histinit(const int* __restrict__ ei, int* __restrict__ deg,
                           int* __restrict__ rel_e,
                           const float* __restrict__ We, const float* __restrict__ be,
                           __half* __restrict__ we2t) {
    int e = blockIdx.x * blockDim.x + threadIdx.x;
    if (e < NE) rel_e[e] = atomicAdd(&deg[ei[NE + e]], 1);
    if (e < 16 * 544) {
        int k = e % 544, m = e / 544;
        float v;
        if (k < 512) {
            int ks = k >> 5, r = k & 31, q = r >> 3, j = r & 7;
            int f = 16 * (q >> 1) + ks;
            int i = (q & 1) * 8 + j;
            v = We[f * 256 + i * 16 + m];
        } else if (k < 528) {
            int i = k - 512;
            v = be[i * 16 + m];
        } else v = 0.f;
        we2t[e] = __float2half(v);
    }
}

// ---------------- K0b: single-block exclusive scan of deg -> cstart (int4 loads) ----------------
#define SCAN_K 20
__global__ __launch_bounds__(1024) void k_scan(const int* __restrict__ deg, int* __restrict__ cstart) {
    __shared__ int sd[1024];
    int t = threadIdx.x;
    int base = t * SCAN_K;
    int vals[SCAN_K];
    int s = 0;
    if (base + SCAN_K <= NN) {          // t < 1000 exactly (NN = 20000)
        const int4* dv = (const int4*)(deg + base);
        int4 b[5];
        #pragma unroll
        for (int q = 0; q < 5; ++q) b[q] = dv[q];
        const int* bb = (const int*)b;
        #pragma unroll
        for (int k = 0; k < SCAN_K; ++k) { vals[k] = s; s += bb[k]; }
    } else {
        #pragma unroll
        for (int k = 0; k < SCAN_K; ++k) { vals[k] = s; }
    }
    sd[t] = s; __syncthreads();
    for (int off = 1; off < 1024; off <<= 1) {
        int add = (t >= off) ? sd[t - off] : 0;
        __syncthreads();
        sd[t] += add;
        __syncthreads();
    }
    int excl = (t == 0) ? 0 : sd[t - 1];
    #pragma unroll
    for (int k = 0; k < SCAN_K; ++k) {
        int i = base + k;
        if (i <= NN) cstart[i] = excl + vals[k];
    }
}

// ---------------- K1: NNConv messages; LDS-staged coalesced ea, 1 tile/wave ----------------
#define EA_STRIDE 36   // padded LDS row stride (floats); b128-aligned, spreads banks
__global__ __launch_bounds__(256) void k_msg(
    const float* __restrict__ x, const int* __restrict__ ei,
    const float* __restrict__ ea, const __half* __restrict__ we2t,
    const int* __restrict__ rel_e, const int* __restrict__ cstart,
    float* __restrict__ msg, int* __restrict__ esrc)
{
    __shared__ float lds[4][16 * EA_STRIDE];
    const int lane = threadIdx.x & 63;
    const int wid  = threadIdx.x >> 6;
    const int m    = lane & 15;      // A-row (edge) / C col
    const int quad = lane >> 4;
    const int p    = quad >> 1;      // ea half selector
    const int xh   = (quad & 1) * 8; // x half

    const int tile = blockIdx.x * 4 + wid;   // 5000 blocks x 4 waves = 20000 tiles
    const int e0   = tile * 16;
    const int r    = e0 + quad * 4 + (m & 3);   // C row this lane resolves CSR pos for

    // ---- coalesced ea tile load: 2 x 1KB instructions -> LDS (wave-private) ----
    {
        const int eL = lane >> 3;          // 0..7
        const int fL = (lane & 7) * 4;     // 0,4,..,28
        const float4* src0 = (const float4*)(ea + (long)e0 * 32 + lane * 4);
        const float4* src1 = (const float4*)(ea + (long)e0 * 32 + 256 + lane * 4);
        float4 v0 = *src0;
        float4 v1 = *src1;
        *(float4*)&lds[wid][eL * EA_STRIDE + fL]       = v0;
        *(float4*)&lds[wid][(8 + eL) * EA_STRIDE + fL] = v1;
    }

    // ---- remaining loads ----
    const int s   = ei[e0 + m];
    const int d   = ei[NE + r];
    const int rel = rel_e[r];
    const int src = ei[r];

    float xf[8];
    {
        const float4* xr = (const float4*)(x + s * 16 + xh);
        float4 a0 = xr[0], a1 = xr[1];
        xf[0]=a0.x; xf[1]=a0.y; xf[2]=a0.z; xf[3]=a0.w;
        xf[4]=a1.x; xf[5]=a1.y; xf[6]=a1.z; xf[7]=a1.w;
    }
    const int c = cstart[d] + rel;
    if (m < 4) esrc[c] = src;                 // one writer per C row

    // B fragments: 17 aligned 16B loads from precomputed (K-permuted) f16 table.
    const __half* wt = we2t + m * 544 + quad * 8;
    f16x8 bfr[17];
    #pragma unroll
    for (int ks = 0; ks < 17; ++ks)
        bfr[ks] = *(const f16x8*)(wt + ks * 32);

    // ---- per-lane ea values from LDS: 4 x ds_read_b128 ----
    float4 ev[4];
    #pragma unroll
    for (int q = 0; q < 4; ++q)
        ev[q] = *(const float4*)&lds[wid][m * EA_STRIDE + p * 16 + q * 4];

    __half2 xp[4];
    #pragma unroll
    for (int j = 0; j < 4; ++j)
        xp[j] = __float22half2_rn(make_float2(xf[2*j], xf[2*j+1]));

    f32x4 acc = {0.f, 0.f, 0.f, 0.f};
    #pragma unroll
    for (int ks = 0; ks < 16; ++ks) {
        float evv = ((const float*)ev)[ks];
        __half2 eh = __float2half2_rn(evv);
        AFrag a;
        #pragma unroll
        for (int j = 0; j < 4; ++j) a.h2[j] = __hmul2(eh, xp[j]);
        acc = __builtin_amdgcn_mfma_f32_16x16x32_f16(a.v, bfr[ks], acc, 0, 0, 0);
    }
    {
        AFrag a;
        #pragma unroll
        for (int j = 0; j < 4; ++j) a.h2[j] = xp[j];
        acc = __builtin_amdgcn_mfma_f32_16x16x32_f16(a.v, bfr[16], acc, 0, 0, 0);
    }
    #pragma unroll
    for (int rr = 0; rr < 4; ++rr) {
        int cc = __shfl(c, (quad << 4) | rr);
        msg[(long)cc * 16 + m] = acc[rr];
    }
}

// ---------------- K2: fused NNConv-finish + GAT projection; wave per node ----------------
__global__ __launch_bounds__(256) void k_node(
    const float* __restrict__ x, const float* __restrict__ Wroot,
    const float* __restrict__ bconv, const float* __restrict__ msg,
    const int* __restrict__ cstart, const float* __restrict__ Wgat,
    const float* __restrict__ a_src, const float* __restrict__ a_dst,
    __half* __restrict__ hpb, float* __restrict__ sc_s, float* __restrict__ sc_d)
{
    int n = (blockIdx.x * blockDim.x + threadIdx.x) >> 6;
    int lane = threadIdx.x & 63;
    if (n >= NN) return;
    int o = lane & 15, g4 = lane >> 4;
    int a0 = cstart[n], a1 = cstart[n + 1];
    float part = 0.f;
    for (int j = a0 + g4; j < a1; j += 4) part += msg[(long)j * 16 + o];  // contiguous rows
    part += __shfl_xor(part, 16);
    part += __shfl_xor(part, 32);
    float xv = x[n * 16 + o];
    float acc = bconv[o] + part;
    #pragma unroll
    for (int i = 0; i < 16; ++i) acc += __shfl(xv, i) * Wroot[i * 16 + o];
    float hv = fmaxf(acc, 0.f);                  // replicated across quads
    float hpacc = 0.f;
    #pragma unroll
    for (int i = 0; i < 16; ++i) hpacc += __shfl(hv, i) * Wgat[i * 64 + lane];
    hpb[(long)n * 64 + lane] = __float2half(hpacc);
    float ss = hpacc * a_src[lane];
    float sd = hpacc * a_dst[lane];
    #pragma unroll
    for (int off = 32; off; off >>= 1) {
        ss += __shfl_xor(ss, off);
        sd += __shfl_xor(sd, off);
    }
    if (lane == 0) { sc_s[n] = ss; sc_d[n] = sd; }
}

// ---------------- K3: GAT, wave per node, lane-parallel neighbor softmax ----------------
__global__ __launch_bounds__(256) void k_gat(const __half* __restrict__ hpb,
                     const float* __restrict__ sc_s, const float* __restrict__ sc_d,
                     const int* __restrict__ esrc, const int* __restrict__ cstart,
                     const float* __restrict__ bgat, float* __restrict__ gat) {
    int d = (blockIdx.x * blockDim.x + threadIdx.x) >> 6;
    int lane = threadIdx.x & 63;
    if (d >= NN) return;
    float sdv = sc_d[d];
    float e0 = sc_s[d] + sdv;                 // self loop
    e0 = (e0 >= 0.f) ? e0 : 0.2f * e0;
    float mx = e0, l = 1.f;
    float acc = __half2float(hpb[(long)d * 64 + lane]);
    int a0 = cstart[d], a1 = cstart[d + 1];
    for (int base = a0; base < a1; base += 64) {
        int j = base + lane;
        bool valid = j < a1;
        int s = valid ? esrc[j] : 0;          // coalesced src ids
        float sc = valid ? sc_s[s] + sdv : -1e30f;
        sc = (sc >= 0.f) ? sc : 0.2f * sc;
        float cm = sc;
        #pragma unroll
        for (int off = 32; off; off >>= 1) cm = fmaxf(cm, __shfl_xor(cm, off));
        float nm = fmaxf(mx, cm);
        float pj = valid ? __expf(sc - nm) : 0.f;
        float ps = pj;
        #pragma unroll
        for (int off = 32; off; off >>= 1) ps += __shfl_xor(ps, off);
        float scale = __expf(mx - nm);
        l = l * scale + ps;
        acc *= scale;
        mx = nm;
        int cnt = a1 - base; if (cnt > 64) cnt = 64;
        int k2 = 0;
        for (; k2 + 4 <= cnt; k2 += 4) {
            int   s0 = __shfl(s, k2),     s1 = __shfl(s, k2 + 1);
            int   s2 = __shfl(s, k2 + 2), s3 = __shfl(s, k2 + 3);
            float p0 = __shfl(pj, k2),     p1 = __shfl(pj, k2 + 1);
            float p2 = __shfl(pj, k2 + 2), p3 = __shfl(pj, k2 + 3);
            float h0 = __half2float(hpb[(long)s0 * 64 + lane]);
            float h1 = __half2float(hpb[(long)s1 * 64 + lane]);
            float h2 = __half2float(hpb[(long)s2 * 64 + lane]);
            float h3 = __half2float(hpb[(long)s3 * 64 + lane]);
            acc += p0 * h0 + p1 * h1 + p2 * h2 + p3 * h3;
        }
        for (; k2 < cnt; ++k2) {
            int sk = __shfl(s, k2);
            float pk = __shfl(pj, k2);
            acc += pk * __half2float(hpb[(long)sk * 64 + lane]);
        }
    }
    float g = acc / l + bgat[lane];
    gat[(long)d * 64 + lane] = fmaxf(g, 0.f);
}

// ---------------- K4: fused mean-pool + MLP head; one block per graph ----------------
static __device__ inline int lbound(const int* b, int key) {
    int lo = 0, hi = NN;
    while (lo < hi) { int mid = (lo + hi) >> 1; if (b[mid] < key) lo = mid + 1; else hi = mid; }
    return lo;
}
__global__ __launch_bounds__(256) void k_poolhead(
    const float* __restrict__ gat, const int* __restrict__ batch,
    const float* __restrict__ Wfc1, const float* __restrict__ bfc1,
    const float* __restrict__ Wfc2, const float* __restrict__ bfc2,
    float* __restrict__ out)
{
    int g = blockIdx.x;
    int t = threadIdx.x;
    int r0 = lbound(batch, g);
    int r1 = lbound(batch, g + 1);
    int o = t & 63, gr = t >> 6;
    float part = 0.f;
    for (int r = r0 + gr; r < r1; r += 4) part += gat[(long)r * 64 + o];
    __shared__ float sd[256];
    __shared__ float pooled[64];
    __shared__ float zl[128];
    sd[t] = part; __syncthreads();
    if (t < 64) {
        float tot = sd[t] + sd[64 + t] + sd[128 + t] + sd[192 + t];
        int cnt = r1 - r0;
        pooled[t] = tot / (float)(cnt > 0 ? cnt : 1);
    }
    __syncthreads();
    if (t < 128) {
        float a = bfc1[t];
        #pragma unroll 8
        for (int i = 0; i < 64; ++i) a += pooled[i] * Wfc1[i * 128 + t];
        zl[t] = fmaxf(a, 0.f);
    }
    __syncthreads();
    if (t < 64) {
        float v = zl[t] * Wfc2[t] + zl[t + 64] * Wfc2[t + 64];
        #pragma unroll
        for (int off = 32; off; off >>= 1) v += __shfl_xor(v, off);
        if (t == 0) out[g] = v + bfc2[0];
    }
}

extern "C" void kernel_launch(void* const* d_in, const int* in_sizes, int n_in,
                              void* d_out, int out_size, void* d_ws, size_t ws_size,
                              hipStream_t stream) {
    (void)in_sizes; (void)n_in; (void)out_size; (void)ws_size;
    const float* x     = (const float*)d_in[0];
    const int*   ei    = (const int*)d_in[1];
    const float* ea    = (const float*)d_in[2];
    const int*   batch = (const int*)d_in[3];
    const float* We    = (const float*)d_in[4];
    const float* be    = (const float*)d_in[5];
    const float* Wroot = (const float*)d_in[6];
    const float* bconv = (const float*)d_in[7];
    const float* Wgat  = (const float*)d_in[8];
    const float* a_src = (const float*)d_in[9];
    const float* a_dst = (const float*)d_in[10];
    const float* bgat  = (const float*)d_in[11];
    const float* Wfc1  = (const float*)d_in[12];
    const float* bfc1  = (const float*)d_in[13];
    const float* Wfc2  = (const float*)d_in[14];
    const float* bfc2  = (const float*)d_in[15];

    char* w = (char*)d_ws;
    size_t o0  = 0;                            // deg      NN int
    size_t o1  = o0  + (size_t)NN * 4;         // cstart   (NN+1) int
    size_t o2  = o1  + (size_t)(NN + 1) * 4;   // rel_e    NE int
    size_t o3  = o2  + (size_t)NE * 4;         // esrc     NE int
    size_t o4  = o3  + (size_t)NE * 4;         // msg      NE*16 f32 (CSR order)
    size_t o5  = o4  + (size_t)NE * 16 * 4;    // hpb      NN*64 f16
    size_t o6  = o5  + (size_t)NN * 64 * 2;    // sc_s     NN f32
    size_t o7  = o6  + (size_t)NN * 4;         // sc_d     NN f32
    size_t o8  = o7  + (size_t)NN * 4;         // gat      NN*64 f32
    size_t o9  = o8  + (size_t)NN * 64 * 4;    // we2t     16*544 f16
    o9 = (o9 + 15) & ~(size_t)15;

    int* deg      = (int*)(w + o0);
    int* cstart   = (int*)(w + o1);
    int* rel_e    = (int*)(w + o2);
    int* esrc     = (int*)(w + o3);
    float* msg    = (float*)(w + o4);
    __half* hpb   = (__half*)(w + o5);
    float* sc_s   = (float*)(w + o6);
    float* sc_d   = (float*)(w + o7);
    float* gat    = (float*)(w + o8);
    __half* we2t  = (__half*)(w + o9);

    (void)hipMemsetAsync(deg, 0, (size_t)NN * 4, stream);
    k_histinit<<<(NE + 255) / 256, 256, 0, stream>>>(ei, deg, rel_e, We, be, we2t);
    k_scan<<<1, 1024, 0, stream>>>(deg, cstart);
    k_msg<<<5000, 256, 0, stream>>>(x, ei, ea, we2t, rel_e, cstart, msg, esrc);
    k_node<<<(NN + 3) / 4, 256, 0, stream>>>(x, Wroot, bconv, msg, cstart, Wgat, a_src, a_dst,
                                             hpb, sc_s, sc_d);
    k_gat<<<(NN + 3) / 4, 256, 0, stream>>>(hpb, sc_s, sc_d, esrc, cstart, bgat, gat);
    k_poolhead<<<NG, 256, 0, stream>>>(gat, batch, Wfc1, bfc1, Wfc2, bfc2, (float*)d_out);
}

// Round 10
// 226.423 us; speedup vs baseline: 1.3913x; 1.0200x over previous
//
#include <hip/hip_runtime.h>
#include <hip/hip_bf16.h>
#include <hip/hip_fp16.h>

#define NN 20000      // nodes
#define NE 320000     // edges
#define FE 32         // edge feature dim
#define DIN 16
#define DNN 16
#define DGAT 64
#define HID 128
#define NG 64         // graphs

using f16x8 = __attribute__((ext_vector_type(8))) _Float16;
using f32x4 = __attribute__((ext_vector_type(4))) float;

union AFrag {
    f16x8 v;
    __half2 h2[4];
};

// ---------------- K0: fused histogram (rel position) + we2t build ----------------
// K permutation (owned by us, A and B agree): for k in [0,512):
//   ks=k>>5, r=k&31, q=r>>3, j=r&7 ; f = 16*(q>>1) + ks ; i = (q&1)*8 + j
// so a lane (quad q) needs ea[e, p*16 + ks], ks=0..15.
// k in [512,528): bias row i=k-512 ; k in [528,544): zero.
__global__ void k_histinit(const int* __restrict__ ei, int* __restrict__ deg,
                           int* __restrict__ rel_e,
                           const float* __restrict__ We, const float* __restrict__ be,
                           __half* __restrict__ we2t) {
    int e = blockIdx.x * blockDim.x + threadIdx.x;
    if (e < NE) rel_e[e] = atomicAdd(&deg[ei[NE + e]], 1);
    if (e < 16 * 544) {
        int k = e % 544, m = e / 544;
        float v;
        if (k < 512) {
            int ks = k >> 5, r = k & 31, q = r >> 3, j = r & 7;
            int f = 16 * (q >> 1) + ks;
            int i = (q & 1) * 8 + j;
            v = We[f * 256 + i * 16 + m];
        } else if (k < 528) {
            int i = k - 512;
            v = be[i * 16 + m];
        } else v = 0.f;
        we2t[e] = __float2half(v);
    }
}

// ---------------- K0b: single-block scan (shuffle-based, 2 barriers) ----------------
#define SCAN_K 20
__global__ __launch_bounds__(1024) void k_scan(const int* __restrict__ deg, int* __restrict__ cstart) {
    __shared__ int wsum[16];
    int t = threadIdx.x;
    int lane = t & 63, wv = t >> 6;
    int base = t * SCAN_K;
    int vals[SCAN_K];
    int s = 0;
    if (base + SCAN_K <= NN) {          // t < 1000 exactly (NN = 20000)
        const int4* dv = (const int4*)(deg + base);
        int4 b[5];
        #pragma unroll
        for (int q = 0; q < 5; ++q) b[q] = dv[q];
        const int* bb = (const int*)b;
        #pragma unroll
        for (int k = 0; k < SCAN_K; ++k) { vals[k] = s; s += bb[k]; }
    } else {
        #pragma unroll
        for (int k = 0; k < SCAN_K; ++k) vals[k] = 0;
    }
    // inclusive scan of s across the wave
    int isum = s;
    #pragma unroll
    for (int off = 1; off < 64; off <<= 1) {
        int v = __shfl_up(isum, off);
        if (lane >= off) isum += v;
    }
    if (lane == 63) wsum[wv] = isum;
    __syncthreads();
    if (t < 16) {
        int wval = wsum[t];
        #pragma unroll
        for (int off = 1; off < 16; off <<= 1) {
            int v = __shfl_up(wval, off);
            if (t >= off) wval += v;
        }
        wsum[t] = wval;   // inclusive wave totals
    }
    __syncthreads();
    int excl = ((wv == 0) ? 0 : wsum[wv - 1]) + (isum - s);
    #pragma unroll
    for (int k = 0; k < SCAN_K; ++k) {
        int i = base + k;
        if (i <= NN) cstart[i] = excl + vals[k];
    }
}

// ---------------- K1: NNConv messages; persistent 4-tile waves, LDS-dbuf ea prefetch ----------------
#define EA_STRIDE 36   // padded LDS row stride (floats); b128-aligned, spreads banks
#define TPW 4          // tiles per wave
__global__ __launch_bounds__(256) void k_msg(
    const float* __restrict__ x, const int* __restrict__ ei,
    const float* __restrict__ ea, const __half* __restrict__ we2t,
    const int* __restrict__ rel_e, const int* __restrict__ cstart,
    float* __restrict__ msg, int* __restrict__ esrc)
{
    __shared__ float lds[4][2][16 * EA_STRIDE];
    const int lane = threadIdx.x & 63;
    const int wid  = threadIdx.x >> 6;
    const int m    = lane & 15;      // A-row (edge) / C col
    const int quad = lane >> 4;
    const int p    = quad >> 1;      // ea half selector
    const int xh   = (quad & 1) * 8; // x half
    const int eL   = lane >> 3;      // staging: edge 0..7
    const int fL   = (lane & 7) * 4; // staging: feature offset

    const int gw = blockIdx.x * 4 + wid;   // 1250 blocks x 4 waves = 5000 waves
    const int t0 = gw * TPW;               // 4 contiguous tiles per wave

    // B fragments ONCE per wave: 17 aligned 16B loads from K-permuted f16 table.
    const __half* wt = we2t + m * 544 + quad * 8;
    f16x8 bfr[17];
    #pragma unroll
    for (int ks = 0; ks < 17; ++ks)
        bfr[ks] = *(const f16x8*)(wt + ks * 32);

    // prologue: stage tile0 ea -> LDS buf0 (two coalesced 1KB loads)
    {
        const float4* s0 = (const float4*)(ea + (long)t0 * 512 + lane * 4);
        float4 v0 = s0[0];
        float4 v1 = s0[64];
        *(float4*)&lds[wid][0][eL * EA_STRIDE + fL]       = v0;
        *(float4*)&lds[wid][0][(8 + eL) * EA_STRIDE + fL] = v1;
    }

    int buf = 0;
    for (int it = 0; it < TPW; ++it) {
        const int tile = t0 + it;
        const int e0   = tile * 16;
        const int r    = e0 + quad * 4 + (m & 3);   // C row this lane resolves CSR pos for

        // prefetch next tile's ea into registers (consumed after compute)
        float4 nv0, nv1;
        if (it < TPW - 1) {
            const float4* sn = (const float4*)(ea + (long)(tile + 1) * 512 + lane * 4);
            nv0 = sn[0];
            nv1 = sn[64];
        }

        const int s   = ei[e0 + m];
        const int d   = ei[NE + r];
        const int rel = rel_e[r];
        const int src = ei[r];

        float xf[8];
        {
            const float4* xr = (const float4*)(x + s * 16 + xh);
            float4 a0 = xr[0], a1 = xr[1];
            xf[0]=a0.x; xf[1]=a0.y; xf[2]=a0.z; xf[3]=a0.w;
            xf[4]=a1.x; xf[5]=a1.y; xf[6]=a1.z; xf[7]=a1.w;
        }
        const int c = cstart[d] + rel;
        if (m < 4) esrc[c] = src;                 // one writer per C row

        // per-lane ea values from LDS: 4 x ds_read_b128
        float4 ev[4];
        #pragma unroll
        for (int q = 0; q < 4; ++q)
            ev[q] = *(const float4*)&lds[wid][buf][m * EA_STRIDE + p * 16 + q * 4];

        __half2 xp[4];
        #pragma unroll
        for (int j = 0; j < 4; ++j)
            xp[j] = __float22half2_rn(make_float2(xf[2*j], xf[2*j+1]));

        f32x4 acc = {0.f, 0.f, 0.f, 0.f};
        #pragma unroll
        for (int ks = 0; ks < 16; ++ks) {
            float evv = ((const float*)ev)[ks];
            __half2 eh = __float2half2_rn(evv);
            AFrag a;
            #pragma unroll
            for (int j = 0; j < 4; ++j) a.h2[j] = __hmul2(eh, xp[j]);
            acc = __builtin_amdgcn_mfma_f32_16x16x32_f16(a.v, bfr[ks], acc, 0, 0, 0);
        }
        {
            AFrag a;
            #pragma unroll
            for (int j = 0; j < 4; ++j) a.h2[j] = xp[j];
            acc = __builtin_amdgcn_mfma_f32_16x16x32_f16(a.v, bfr[16], acc, 0, 0, 0);
        }
        #pragma unroll
        for (int rr = 0; rr < 4; ++rr) {
            int cc = __shfl(c, (quad << 4) | rr);
            msg[(long)cc * 16 + m] = acc[rr];
        }

        // publish prefetched ea into the other buffer (same wave: no barrier needed)
        if (it < TPW - 1) {
            buf ^= 1;
            *(float4*)&lds[wid][buf][eL * EA_STRIDE + fL]       = nv0;
            *(float4*)&lds[wid][buf][(8 + eL) * EA_STRIDE + fL] = nv1;
        }
    }
}

// ---------------- K2: fused NNConv-finish + GAT projection; wave per node ----------------
__global__ __launch_bounds__(256) void k_node(
    const float* __restrict__ x, const float* __restrict__ Wroot,
    const float* __restrict__ bconv, const float* __restrict__ msg,
    const int* __restrict__ cstart, const float* __restrict__ Wgat,
    const float* __restrict__ a_src, const float* __restrict__ a_dst,
    __half* __restrict__ hpb, float* __restrict__ sc_s, float* __restrict__ sc_d)
{
    int n = (blockIdx.x * blockDim.x + threadIdx.x) >> 6;
    int lane = threadIdx.x & 63;
    if (n >= NN) return;
    int o = lane & 15, g4 = lane >> 4;
    int a0 = cstart[n], a1 = cstart[n + 1];
    float part = 0.f;
    for (int j = a0 + g4; j < a1; j += 4) part += msg[(long)j * 16 + o];  // contiguous rows
    part += __shfl_xor(part, 16);
    part += __shfl_xor(part, 32);
    float xv = x[n * 16 + o];
    float acc = bconv[o] + part;
    #pragma unroll
    for (int i = 0; i < 16; ++i) acc += __shfl(xv, i) * Wroot[i * 16 + o];
    float hv = fmaxf(acc, 0.f);                  // replicated across quads
    float hpacc = 0.f;
    #pragma unroll
    for (int i = 0; i < 16; ++i) hpacc += __shfl(hv, i) * Wgat[i * 64 + lane];
    hpb[(long)n * 64 + lane] = __float2half(hpacc);
    float ss = hpacc * a_src[lane];
    float sd = hpacc * a_dst[lane];
    #pragma unroll
    for (int off = 32; off; off >>= 1) {
        ss += __shfl_xor(ss, off);
        sd += __shfl_xor(sd, off);
    }
    if (lane == 0) { sc_s[n] = ss; sc_d[n] = sd; }
}

// ---------------- K3: GAT, wave per node, lane-parallel neighbor softmax ----------------
__global__ __launch_bounds__(256) void k_gat(const __half* __restrict__ hpb,
                     const float* __restrict__ sc_s, const float* __restrict__ sc_d,
                     const int* __restrict__ esrc, const int* __restrict__ cstart,
                     const float* __restrict__ bgat, float* __restrict__ gat) {
    int d = (blockIdx.x * blockDim.x + threadIdx.x) >> 6;
    int lane = threadIdx.x & 63;
    if (d >= NN) return;
    float sdv = sc_d[d];
    float e0 = sc_s[d] + sdv;                 // self loop
    e0 = (e0 >= 0.f) ? e0 : 0.2f * e0;
    float mx = e0, l = 1.f;
    float acc = __half2float(hpb[(long)d * 64 + lane]);
    int a0 = cstart[d], a1 = cstart[d + 1];
    for (int base = a0; base < a1; base += 64) {
        int j = base + lane;
        bool valid = j < a1;
        int s = valid ? esrc[j] : 0;          // coalesced src ids
        float sc = valid ? sc_s[s] + sdv : -1e30f;
        sc = (sc >= 0.f) ? sc : 0.2f * sc;
        float cm = sc;
        #pragma unroll
        for (int off = 32; off; off >>= 1) cm = fmaxf(cm, __shfl_xor(cm, off));
        float nm = fmaxf(mx, cm);
        float pj = valid ? __expf(sc - nm) : 0.f;
        float ps = pj;
        #pragma unroll
        for (int off = 32; off; off >>= 1) ps += __shfl_xor(ps, off);
        float scale = __expf(mx - nm);
        l = l * scale + ps;
        acc *= scale;
        mx = nm;
        int cnt = a1 - base; if (cnt > 64) cnt = 64;
        int k2 = 0;
        for (; k2 + 4 <= cnt; k2 += 4) {
            int   s0 = __shfl(s, k2),     s1 = __shfl(s, k2 + 1);
            int   s2 = __shfl(s, k2 + 2), s3 = __shfl(s, k2 + 3);
            float p0 = __shfl(pj, k2),     p1 = __shfl(pj, k2 + 1);
            float p2 = __shfl(pj, k2 + 2), p3 = __shfl(pj, k2 + 3);
            float h0 = __half2float(hpb[(long)s0 * 64 + lane]);
            float h1 = __half2float(hpb[(long)s1 * 64 + lane]);
            float h2 = __half2float(hpb[(long)s2 * 64 + lane]);
            float h3 = __half2float(hpb[(long)s3 * 64 + lane]);
            acc += p0 * h0 + p1 * h1 + p2 * h2 + p3 * h3;
        }
        for (; k2 < cnt; ++k2) {
            int sk = __shfl(s, k2);
            float pk = __shfl(pj, k2);
            acc += pk * __half2float(hpb[(long)sk * 64 + lane]);
        }
    }
    float g = acc / l + bgat[lane];
    gat[(long)d * 64 + lane] = fmaxf(g, 0.f);
}

// ---------------- K4: fused mean-pool + MLP head; one block per graph ----------------
static __device__ inline int lbound(const int* b, int key) {
    int lo = 0, hi = NN;
    while (lo < hi) { int mid = (lo + hi) >> 1; if (b[mid] < key) lo = mid + 1; else hi = mid; }
    return lo;
}
__global__ __launch_bounds__(256) void k_poolhead(
    const float* __restrict__ gat, const int* __restrict__ batch,
    const float* __restrict__ Wfc1, const float* __restrict__ bfc1,
    const float* __restrict__ Wfc2, const float* __restrict__ bfc2,
    float* __restrict__ out)
{
    int g = blockIdx.x;
    int t = threadIdx.x;
    int r0 = lbound(batch, g);
    int r1 = lbound(batch, g + 1);
    int o = t & 63, gr = t >> 6;
    float part = 0.f;
    for (int r = r0 + gr; r < r1; r += 4) part += gat[(long)r * 64 + o];
    __shared__ float sd[256];
    __shared__ float pooled[64];
    __shared__ float zl[128];
    sd[t] = part; __syncthreads();
    if (t < 64) {
        float tot = sd[t] + sd[64 + t] + sd[128 + t] + sd[192 + t];
        int cnt = r1 - r0;
        pooled[t] = tot / (float)(cnt > 0 ? cnt : 1);
    }
    __syncthreads();
    if (t < 128) {
        float a = bfc1[t];
        #pragma unroll 8
        for (int i = 0; i < 64; ++i) a += pooled[i] * Wfc1[i * 128 + t];
        zl[t] = fmaxf(a, 0.f);
    }
    __syncthreads();
    if (t < 64) {
        float v = zl[t] * Wfc2[t] + zl[t + 64] * Wfc2[t + 64];
        #pragma unroll
        for (int off = 32; off; off >>= 1) v += __shfl_xor(v, off);
        if (t == 0) out[g] = v + bfc2[0];
    }
}

extern "C" void kernel_launch(void* const* d_in, const int* in_sizes, int n_in,
                              void* d_out, int out_size, void* d_ws, size_t ws_size,
                              hipStream_t stream) {
    (void)in_sizes; (void)n_in; (void)out_size; (void)ws_size;
    const float* x     = (const float*)d_in[0];
    const int*   ei    = (const int*)d_in[1];
    const float* ea    = (const float*)d_in[2];
    const int*   batch = (const int*)d_in[3];
    const float* We    = (const float*)d_in[4];
    const float* be    = (const float*)d_in[5];
    const float* Wroot = (const float*)d_in[6];
    const float* bconv = (const float*)d_in[7];
    const float* Wgat  = (const float*)d_in[8];
    const float* a_src = (const float*)d_in[9];
    const float* a_dst = (const float*)d_in[10];
    const float* bgat  = (const float*)d_in[11];
    const float* Wfc1  = (const float*)d_in[12];
    const float* bfc1  = (const float*)d_in[13];
    const float* Wfc2  = (const float*)d_in[14];
    const float* bfc2  = (const float*)d_in[15];

    char* w = (char*)d_ws;
    size_t o0  = 0;                            // deg      NN int
    size_t o1  = o0  + (size_t)NN * 4;         // cstart   (NN+1) int
    size_t o2  = o1  + (size_t)(NN + 1) * 4;   // rel_e    NE int
    size_t o3  = o2  + (size_t)NE * 4;         // esrc     NE int
    size_t o4  = o3  + (size_t)NE * 4;         // msg      NE*16 f32 (CSR order)
    size_t o5  = o4  + (size_t)NE * 16 * 4;    // hpb      NN*64 f16
    size_t o6  = o5  + (size_t)NN * 64 * 2;    // sc_s     NN f32
    size_t o7  = o6  + (size_t)NN * 4;         // sc_d     NN f32
    size_t o8  = o7  + (size_t)NN * 4;         // gat      NN*64 f32
    size_t o9  = o8  + (size_t)NN * 64 * 4;    // we2t     16*544 f16
    o9 = (o9 + 15) & ~(size_t)15;

    int* deg      = (int*)(w + o0);
    int* cstart   = (int*)(w + o1);
    int* rel_e    = (int*)(w + o2);
    int* esrc     = (int*)(w + o3);
    float* msg    = (float*)(w + o4);
    __half* hpb   = (__half*)(w + o5);
    float* sc_s   = (float*)(w + o6);
    float* sc_d   = (float*)(w + o7);
    float* gat    = (float*)(w + o8);
    __half* we2t  = (__half*)(w + o9);

    (void)hipMemsetAsync(deg, 0, (size_t)NN * 4, stream);
    k_histinit<<<(NE + 255) / 256, 256, 0, stream>>>(ei, deg, rel_e, We, be, we2t);
    k_scan<<<1, 1024, 0, stream>>>(deg, cstart);
    k_msg<<<1250, 256, 0, stream>>>(x, ei, ea, we2t, rel_e, cstart, msg, esrc);
    k_node<<<(NN + 3) / 4, 256, 0, stream>>>(x, Wroot, bconv, msg, cstart, Wgat, a_src, a_dst,
                                             hpb, sc_s, sc_d);
    k_gat<<<(NN + 3) / 4, 256, 0, stream>>>(hpb, sc_s, sc_d, esrc, cstart, bgat, gat);
    k_poolhead<<<NG, 256, 0, stream>>>(gat, batch, Wfc1, bfc1, Wfc2, bfc2, (float*)d_out);
}

// Round 11
// 215.298 us; speedup vs baseline: 1.4632x; 1.0517x over previous
//
#include <hip/hip_runtime.h>
#include <hip/hip_bf16.h>
#include <hip/hip_fp16.h>

#define NN 20000      // nodes
#define NE 320000     // edges
#define FE 32         // edge feature dim
#define DIN 16
#define DNN 16
#define DGAT 64
#define HID 128
#define NG 64         // graphs

using f16x8 = __attribute__((ext_vector_type(8))) _Float16;
using f32x4 = __attribute__((ext_vector_type(4))) float;

union AFrag {
    f16x8 v;
    __half2 h2[4];
};

// ---------------- K0: fused histogram (rel position) + we2t build ----------------
// K permutation (owned by us, A and B agree): for k in [0,512):
//   ks=k>>5, r=k&31, q=r>>3, j=r&7 ; f = 16*(q>>1) + ks ; i = (q&1)*8 + j
// k in [512,528): bias row i=k-512 ; k in [528,544): zero.
__global__ void k_histinit(const int* __restrict__ ei, int* __restrict__ deg,
                           int* __restrict__ rel_e,
                           const float* __restrict__ We, const float* __restrict__ be,
                           __half* __restrict__ we2t) {
    int e = blockIdx.x * blockDim.x + threadIdx.x;
    if (e < NE) rel_e[e] = atomicAdd(&deg[ei[NE + e]], 1);
    if (e < 16 * 544) {
        int k = e % 544, m = e / 544;
        float v;
        if (k < 512) {
            int ks = k >> 5, r = k & 31, q = r >> 3, j = r & 7;
            int f = 16 * (q >> 1) + ks;
            int i = (q & 1) * 8 + j;
            v = We[f * 256 + i * 16 + m];
        } else if (k < 528) {
            int i = k - 512;
            v = be[i * 16 + m];
        } else v = 0.f;
        we2t[e] = __float2half(v);
    }
}

// ---------------- K0b: single-block scan (shuffle-based, 2 barriers) ----------------
#define SCAN_K 20
__global__ __launch_bounds__(1024) void k_scan(const int* __restrict__ deg, int* __restrict__ cstart) {
    __shared__ int wsum[16];
    int t = threadIdx.x;
    int lane = t & 63, wv = t >> 6;
    int base = t * SCAN_K;
    int vals[SCAN_K];
    int s = 0;
    if (base + SCAN_K <= NN) {          // t < 1000 exactly (NN = 20000)
        const int4* dv = (const int4*)(deg + base);
        int4 b[5];
        #pragma unroll
        for (int q = 0; q < 5; ++q) b[q] = dv[q];
        const int* bb = (const int*)b;
        #pragma unroll
        for (int k = 0; k < SCAN_K; ++k) { vals[k] = s; s += bb[k]; }
    } else {
        #pragma unroll
        for (int k = 0; k < SCAN_K; ++k) vals[k] = 0;
    }
    int isum = s;
    #pragma unroll
    for (int off = 1; off < 64; off <<= 1) {
        int v = __shfl_up(isum, off);
        if (lane >= off) isum += v;
    }
    if (lane == 63) wsum[wv] = isum;
    __syncthreads();
    if (t < 16) {
        int wval = wsum[t];
        #pragma unroll
        for (int off = 1; off < 16; off <<= 1) {
            int v = __shfl_up(wval, off);
            if (t >= off) wval += v;
        }
        wsum[t] = wval;
    }
    __syncthreads();
    int excl = ((wv == 0) ? 0 : wsum[wv - 1]) + (isum - s);
    #pragma unroll
    for (int k = 0; k < SCAN_K; ++k) {
        int i = base + k;
        if (i <= NN) cstart[i] = excl + vals[k];
    }
}

// ---------------- K1: NNConv messages; persistent 4-tile waves; ATOMIC aggregation ----------------
// msg buffer eliminated: C rows are atomically accumulated into agg[dst][o] (fp32, L2-resident).
#define EA_STRIDE 36   // padded LDS row stride (floats)
#define TPW 4          // tiles per wave
__global__ __launch_bounds__(256) void k_msg(
    const float* __restrict__ x, const int* __restrict__ ei,
    const float* __restrict__ ea, const __half* __restrict__ we2t,
    const int* __restrict__ rel_e, const int* __restrict__ cstart,
    float* __restrict__ agg, int* __restrict__ esrc)
{
    __shared__ float lds[4][2][16 * EA_STRIDE];
    const int lane = threadIdx.x & 63;
    const int wid  = threadIdx.x >> 6;
    const int m    = lane & 15;      // A-row (edge) / C col
    const int quad = lane >> 4;
    const int p    = quad >> 1;      // ea half selector
    const int xh   = (quad & 1) * 8; // x half
    const int eL   = lane >> 3;      // staging: edge 0..7
    const int fL   = (lane & 7) * 4; // staging: feature offset

    const int gw = blockIdx.x * 4 + wid;   // 1250 blocks x 4 waves = 5000 waves
    const int t0 = gw * TPW;

    // B fragments ONCE per wave
    const __half* wt = we2t + m * 544 + quad * 8;
    f16x8 bfr[17];
    #pragma unroll
    for (int ks = 0; ks < 17; ++ks)
        bfr[ks] = *(const f16x8*)(wt + ks * 32);

    // prologue: stage tile0 ea -> LDS buf0
    {
        const float4* s0 = (const float4*)(ea + (long)t0 * 512 + lane * 4);
        float4 v0 = s0[0];
        float4 v1 = s0[64];
        *(float4*)&lds[wid][0][eL * EA_STRIDE + fL]       = v0;
        *(float4*)&lds[wid][0][(8 + eL) * EA_STRIDE + fL] = v1;
    }

    int buf = 0;
    for (int it = 0; it < TPW; ++it) {
        const int tile = t0 + it;
        const int e0   = tile * 16;
        const int r    = e0 + quad * 4 + (m & 3);   // row this lane resolves dst/CSR for

        float4 nv0, nv1;
        if (it < TPW - 1) {
            const float4* sn = (const float4*)(ea + (long)(tile + 1) * 512 + lane * 4);
            nv0 = sn[0];
            nv1 = sn[64];
        }

        const int s   = ei[e0 + m];
        const int d   = ei[NE + r];
        const int rel = rel_e[r];
        const int src = ei[r];

        float xf[8];
        {
            const float4* xr = (const float4*)(x + s * 16 + xh);
            float4 a0 = xr[0], a1 = xr[1];
            xf[0]=a0.x; xf[1]=a0.y; xf[2]=a0.z; xf[3]=a0.w;
            xf[4]=a1.x; xf[5]=a1.y; xf[6]=a1.z; xf[7]=a1.w;
        }
        const int c = cstart[d] + rel;
        if (m < 4) esrc[c] = src;                 // one writer per CSR slot (for k_gat)

        float4 ev[4];
        #pragma unroll
        for (int q = 0; q < 4; ++q)
            ev[q] = *(const float4*)&lds[wid][buf][m * EA_STRIDE + p * 16 + q * 4];

        __half2 xp[4];
        #pragma unroll
        for (int j = 0; j < 4; ++j)
            xp[j] = __float22half2_rn(make_float2(xf[2*j], xf[2*j+1]));

        f32x4 acc = {0.f, 0.f, 0.f, 0.f};
        #pragma unroll
        for (int ks = 0; ks < 16; ++ks) {
            float evv = ((const float*)ev)[ks];
            __half2 eh = __float2half2_rn(evv);
            AFrag a;
            #pragma unroll
            for (int j = 0; j < 4; ++j) a.h2[j] = __hmul2(eh, xp[j]);
            acc = __builtin_amdgcn_mfma_f32_16x16x32_f16(a.v, bfr[ks], acc, 0, 0, 0);
        }
        {
            AFrag a;
            #pragma unroll
            for (int j = 0; j < 4; ++j) a.h2[j] = xp[j];
            acc = __builtin_amdgcn_mfma_f32_16x16x32_f16(a.v, bfr[16], acc, 0, 0, 0);
        }
        // atomic aggregation: row quad*4+rr has dst = shfl(d, quad*16+rr)
        #pragma unroll
        for (int rr = 0; rr < 4; ++rr) {
            int dd = __shfl(d, (quad << 4) | rr);
            atomicAdd(&agg[dd * 16 + m], acc[rr]);
        }

        if (it < TPW - 1) {
            buf ^= 1;
            *(float4*)&lds[wid][buf][eL * EA_STRIDE + fL]       = nv0;
            *(float4*)&lds[wid][buf][(8 + eL) * EA_STRIDE + fL] = nv1;
        }
    }
}

// ---------------- K2: fused NNConv-finish + GAT projection; wave per node ----------------
__global__ __launch_bounds__(256) void k_node(
    const float* __restrict__ x, const float* __restrict__ Wroot,
    const float* __restrict__ bconv, const float* __restrict__ agg,
    const float* __restrict__ Wgat,
    const float* __restrict__ a_src, const float* __restrict__ a_dst,
    __half* __restrict__ hpb, float* __restrict__ sc_s, float* __restrict__ sc_d)
{
    int n = (blockIdx.x * blockDim.x + threadIdx.x) >> 6;
    int lane = threadIdx.x & 63;
    if (n >= NN) return;
    int o = lane & 15;
    float agv = agg[n * 16 + o];                 // replicated across quads (broadcast)
    float xv = x[n * 16 + o];
    float acc = bconv[o] + agv;
    #pragma unroll
    for (int i = 0; i < 16; ++i) acc += __shfl(xv, i) * Wroot[i * 16 + o];
    float hv = fmaxf(acc, 0.f);
    float hpacc = 0.f;
    #pragma unroll
    for (int i = 0; i < 16; ++i) hpacc += __shfl(hv, i) * Wgat[i * 64 + lane];
    hpb[(long)n * 64 + lane] = __float2half(hpacc);
    float ss = hpacc * a_src[lane];
    float sd = hpacc * a_dst[lane];
    #pragma unroll
    for (int off = 32; off; off >>= 1) {
        ss += __shfl_xor(ss, off);
        sd += __shfl_xor(sd, off);
    }
    if (lane == 0) { sc_s[n] = ss; sc_d[n] = sd; }
}

// ---------------- K3: GAT, wave per node, lane-parallel neighbor softmax ----------------
__global__ __launch_bounds__(256) void k_gat(const __half* __restrict__ hpb,
                     const float* __restrict__ sc_s, const float* __restrict__ sc_d,
                     const int* __restrict__ esrc, const int* __restrict__ cstart,
                     const float* __restrict__ bgat, float* __restrict__ gat) {
    int d = (blockIdx.x * blockDim.x + threadIdx.x) >> 6;
    int lane = threadIdx.x & 63;
    if (d >= NN) return;
    float sdv = sc_d[d];
    float e0 = sc_s[d] + sdv;                 // self loop
    e0 = (e0 >= 0.f) ? e0 : 0.2f * e0;
    float mx = e0, l = 1.f;
    float acc = __half2float(hpb[(long)d * 64 + lane]);
    int a0 = cstart[d], a1 = cstart[d + 1];
    for (int base = a0; base < a1; base += 64) {
        int j = base + lane;
        bool valid = j < a1;
        int s = valid ? esrc[j] : 0;
        float sc = valid ? sc_s[s] + sdv : -1e30f;
        sc = (sc >= 0.f) ? sc : 0.2f * sc;
        float cm = sc;
        #pragma unroll
        for (int off = 32; off; off >>= 1) cm = fmaxf(cm, __shfl_xor(cm, off));
        float nm = fmaxf(mx, cm);
        float pj = valid ? __expf(sc - nm) : 0.f;
        float ps = pj;
        #pragma unroll
        for (int off = 32; off; off >>= 1) ps += __shfl_xor(ps, off);
        float scale = __expf(mx - nm);
        l = l * scale + ps;
        acc *= scale;
        mx = nm;
        int cnt = a1 - base; if (cnt > 64) cnt = 64;
        int k2 = 0;
        for (; k2 + 4 <= cnt; k2 += 4) {
            int   s0 = __shfl(s, k2),     s1 = __shfl(s, k2 + 1);
            int   s2 = __shfl(s, k2 + 2), s3 = __shfl(s, k2 + 3);
            float p0 = __shfl(pj, k2),     p1 = __shfl(pj, k2 + 1);
            float p2 = __shfl(pj, k2 + 2), p3 = __shfl(pj, k2 + 3);
            float h0 = __half2float(hpb[(long)s0 * 64 + lane]);
            float h1 = __half2float(hpb[(long)s1 * 64 + lane]);
            float h2 = __half2float(hpb[(long)s2 * 64 + lane]);
            float h3 = __half2float(hpb[(long)s3 * 64 + lane]);
            acc += p0 * h0 + p1 * h1 + p2 * h2 + p3 * h3;
        }
        for (; k2 < cnt; ++k2) {
            int sk = __shfl(s, k2);
            float pk = __shfl(pj, k2);
            acc += pk * __half2float(hpb[(long)sk * 64 + lane]);
        }
    }
    float g = acc / l + bgat[lane];
    gat[(long)d * 64 + lane] = fmaxf(g, 0.f);
}

// ---------------- K4: fused mean-pool + MLP head; one block per graph ----------------
static __device__ inline int lbound(const int* b, int key) {
    int lo = 0, hi = NN;
    while (lo < hi) { int mid = (lo + hi) >> 1; if (b[mid] < key) lo = mid + 1; else hi = mid; }
    return lo;
}
__global__ __launch_bounds__(256) void k_poolhead(
    const float* __restrict__ gat, const int* __restrict__ batch,
    const float* __restrict__ Wfc1, const float* __restrict__ bfc1,
    const float* __restrict__ Wfc2, const float* __restrict__ bfc2,
    float* __restrict__ out)
{
    int g = blockIdx.x;
    int t = threadIdx.x;
    int r0 = lbound(batch, g);
    int r1 = lbound(batch, g + 1);
    int o = t & 63, gr = t >> 6;
    float part = 0.f;
    for (int r = r0 + gr; r < r1; r += 4) part += gat[(long)r * 64 + o];
    __shared__ float sd[256];
    __shared__ float pooled[64];
    __shared__ float zl[128];
    sd[t] = part; __syncthreads();
    if (t < 64) {
        float tot = sd[t] + sd[64 + t] + sd[128 + t] + sd[192 + t];
        int cnt = r1 - r0;
        pooled[t] = tot / (float)(cnt > 0 ? cnt : 1);
    }
    __syncthreads();
    if (t < 128) {
        float a = bfc1[t];
        #pragma unroll 8
        for (int i = 0; i < 64; ++i) a += pooled[i] * Wfc1[i * 128 + t];
        zl[t] = fmaxf(a, 0.f);
    }
    __syncthreads();
    if (t < 64) {
        float v = zl[t] * Wfc2[t] + zl[t + 64] * Wfc2[t + 64];
        #pragma unroll
        for (int off = 32; off; off >>= 1) v += __shfl_xor(v, off);
        if (t == 0) out[g] = v + bfc2[0];
    }
}

extern "C" void kernel_launch(void* const* d_in, const int* in_sizes, int n_in,
                              void* d_out, int out_size, void* d_ws, size_t ws_size,
                              hipStream_t stream) {
    (void)in_sizes; (void)n_in; (void)out_size; (void)ws_size;
    const float* x     = (const float*)d_in[0];
    const int*   ei    = (const int*)d_in[1];
    const float* ea    = (const float*)d_in[2];
    const int*   batch = (const int*)d_in[3];
    const float* We    = (const float*)d_in[4];
    const float* be    = (const float*)d_in[5];
    const float* Wroot = (const float*)d_in[6];
    const float* bconv = (const float*)d_in[7];
    const float* Wgat  = (const float*)d_in[8];
    const float* a_src = (const float*)d_in[9];
    const float* a_dst = (const float*)d_in[10];
    const float* bgat  = (const float*)d_in[11];
    const float* Wfc1  = (const float*)d_in[12];
    const float* bfc1  = (const float*)d_in[13];
    const float* Wfc2  = (const float*)d_in[14];
    const float* bfc2  = (const float*)d_in[15];

    char* w = (char*)d_ws;
    size_t o0  = 0;                            // deg      NN int      \ zeroed together
    size_t o1  = o0  + (size_t)NN * 4;         // agg      NN*16 f32   /
    size_t o2  = o1  + (size_t)NN * 16 * 4;    // cstart   (NN+1) int
    size_t o3  = o2  + (size_t)(NN + 1) * 4;   // rel_e    NE int
    size_t o4  = o3  + (size_t)NE * 4;         // esrc     NE int
    size_t o5  = o4  + (size_t)NE * 4;         // hpb      NN*64 f16
    size_t o6  = o5  + (size_t)NN * 64 * 2;    // sc_s     NN f32
    size_t o7  = o6  + (size_t)NN * 4;         // sc_d     NN f32
    size_t o8  = o7  + (size_t)NN * 4;         // gat      NN*64 f32
    size_t o9  = o8  + (size_t)NN * 64 * 4;    // we2t     16*544 f16
    o9 = (o9 + 15) & ~(size_t)15;

    int* deg      = (int*)(w + o0);
    float* agg    = (float*)(w + o1);
    int* cstart   = (int*)(w + o2);
    int* rel_e    = (int*)(w + o3);
    int* esrc     = (int*)(w + o4);
    __half* hpb   = (__half*)(w + o5);
    float* sc_s   = (float*)(w + o6);
    float* sc_d   = (float*)(w + o7);
    float* gat    = (float*)(w + o8);
    __half* we2t  = (__half*)(w + o9);

    (void)hipMemsetAsync(w, 0, (size_t)NN * 4 + (size_t)NN * 16 * 4, stream); // deg + agg
    k_histinit<<<(NE + 255) / 256, 256, 0, stream>>>(ei, deg, rel_e, We, be, we2t);
    k_scan<<<1, 1024, 0, stream>>>(deg, cstart);
    k_msg<<<1250, 256, 0, stream>>>(x, ei, ea, we2t, rel_e, cstart, agg, esrc);
    k_node<<<(NN + 3) / 4, 256, 0, stream>>>(x, Wroot, bconv, agg, Wgat, a_src, a_dst,
                                             hpb, sc_s, sc_d);
    k_gat<<<(NN + 3) / 4, 256, 0, stream>>>(hpb, sc_s, sc_d, esrc, cstart, bgat, gat);
    k_poolhead<<<NG, 256, 0, stream>>>(gat, batch, Wfc1, bfc1, Wfc2, bfc2, (float*)d_out);
}